// Round 2
// baseline (1358.501 us; speedup 1.0000x reference)
//
#include <hip/hip_runtime.h>
#include <math.h>

#define N_NODES 100000
#define N_EDGES 1600000
#define NEG 0.2f
#define MAXDEG 128
#define WPB 4   // waves per block for per-node kernels

__device__ __forceinline__ float lrelu(float x){ return x > 0.f ? x : NEG*x; }

// ---------------- degree count ----------------
__global__ __launch_bounds__(256) void k_deg(const int* __restrict__ dst, int* __restrict__ deg){
  int e = blockIdx.x*256 + threadIdx.x;
  if (e < N_EDGES) atomicAdd(&deg[dst[e]], 1);
}

// ---------------- exclusive scan (3 phase) ----------------
__global__ __launch_bounds__(256) void k_scan_a(const int* __restrict__ deg, int* __restrict__ incl, int* __restrict__ bsum){
  __shared__ int s[256];
  int t = threadIdx.x; int i = blockIdx.x*256 + t;
  int v = (i < N_NODES) ? deg[i] : 0;
  s[t] = v; __syncthreads();
  for (int off=1; off<256; off<<=1){
    int u = (t>=off)? s[t-off] : 0; __syncthreads();
    s[t] += u; __syncthreads();
  }
  if (i < N_NODES) incl[i] = s[t];
  if (t == 255) bsum[blockIdx.x] = s[t];
}
__global__ __launch_bounds__(512) void k_scan_b(const int* __restrict__ bsum, int* __restrict__ bexcl, int nb){
  __shared__ int s[512];
  int t = threadIdx.x;
  int v = (t<nb)? bsum[t] : 0;
  s[t] = v; __syncthreads();
  for (int off=1; off<512; off<<=1){
    int u = (t>=off)? s[t-off] : 0; __syncthreads();
    s[t] += u; __syncthreads();
  }
  if (t<nb) bexcl[t] = s[t]-v;
}
__global__ __launch_bounds__(256) void k_scan_c(const int* __restrict__ incl, const int* __restrict__ deg,
    const int* __restrict__ bexcl, int* __restrict__ rowptr){
  int i = blockIdx.x*256+threadIdx.x;
  if (i < N_NODES) rowptr[i] = incl[i] - deg[i] + bexcl[blockIdx.x];
  if (i == 0) rowptr[N_NODES] = N_EDGES;
}

// ---------------- CSR fill ----------------
__global__ __launch_bounds__(256) void k_fill(const int* __restrict__ src, const int* __restrict__ dst,
     const int* __restrict__ rowptr, int* __restrict__ fill, int* __restrict__ csr_src, int* __restrict__ csr_eid){
  int e = blockIdx.x*256+threadIdx.x;
  if (e >= N_EDGES) return;
  int d = dst[e];
  int p = rowptr[d] + atomicAdd(&fill[d], 1);
  csr_src[p] = src[e];
  csr_eid[p] = e;
}

// ---------------- per-node mean of incoming edge_attr ----------------
__global__ __launch_bounds__(256) void k_eamean(const int* __restrict__ rowptr, const int* __restrict__ csr_eid,
    const float* __restrict__ ea, float* __restrict__ ea_mean){
  int w = threadIdx.x >> 6, lane = threadIdx.x & 63;
  int n = blockIdx.x * WPB + w;          // grid is exact: n < N_NODES always
  int j = lane & 15, g = lane >> 4;
  int s0 = rowptr[n]; int deg = rowptr[n+1]-s0;
  float acc = 0.f;
  for (int i=g; i<deg; i+=4) acc += ea[(size_t)csr_eid[s0+i]*16 + j];
  acc += __shfl_xor(acc, 16);
  acc += __shfl_xor(acc, 32);
  if (lane < 16) ea_mean[n*16 + j] = acc / fmaxf((float)deg, 1.f);
}

// ---------------- fp32 GEMM: Y[M,128] = X[M,128] @ W[128,128] (+bias,relu) ----------------
__global__ __launch_bounds__(256) void k_gemm(const float* __restrict__ X, const float* __restrict__ W,
    const float* __restrict__ bias, float* __restrict__ Y, int M, int relu){
  __shared__ float Xs[16][68];     // [kk][row], pad 68 keeps float4 reads aligned, conflicts <= 2-way
  __shared__ float Ws[16][128];
  int t = threadIdx.x;
  int row0 = blockIdx.x * 64;
  int tc = t & 15, tr = t >> 4;
  int c0 = tc*8, r0 = tr*4;
  int lr = t >> 2, lc = (t & 3) << 2; // X staging: row lr, 4 cols at lc
  int wk = t >> 4, wc = (t & 15) * 8; // W staging
  float acc[4][8];
  #pragma unroll
  for (int i=0;i<4;i++)
    #pragma unroll
    for (int j=0;j<8;j++) acc[i][j]=0.f;
  int gr = row0 + lr;
  for (int k0=0; k0<128; k0+=16){
    float4 xv = make_float4(0.f,0.f,0.f,0.f);
    if (gr < M) xv = *(const float4*)(X + (size_t)gr*128 + k0 + lc);
    float4 wv0 = *(const float4*)(W + (size_t)(k0+wk)*128 + wc);
    float4 wv1 = *(const float4*)(W + (size_t)(k0+wk)*128 + wc + 4);
    __syncthreads();
    Xs[lc+0][lr]=xv.x; Xs[lc+1][lr]=xv.y; Xs[lc+2][lr]=xv.z; Xs[lc+3][lr]=xv.w;
    *(float4*)&Ws[wk][wc]   = wv0;
    *(float4*)&Ws[wk][wc+4] = wv1;
    __syncthreads();
    #pragma unroll
    for (int kk=0;kk<16;kk++){
      float4 a  = *(const float4*)&Xs[kk][r0];
      float4 b0 = *(const float4*)&Ws[kk][c0];
      float4 b1 = *(const float4*)&Ws[kk][c0+4];
      float av[4] = {a.x,a.y,a.z,a.w};
      float bv[8] = {b0.x,b0.y,b0.z,b0.w,b1.x,b1.y,b1.z,b1.w};
      #pragma unroll
      for (int i=0;i<4;i++)
        #pragma unroll
        for (int j=0;j<8;j++) acc[i][j] += av[i]*bv[j];
    }
  }
  #pragma unroll
  for (int i=0;i<4;i++){
    int r = row0 + r0 + i;
    if (r < M){
      #pragma unroll
      for (int j=0;j<8;j++){
        float v = acc[i][j] + (bias ? bias[c0+j] : 0.f);
        if (relu) v = fmaxf(v, 0.f);
        Y[(size_t)r*128 + c0 + j] = v;
      }
    }
  }
}

// ---------------- per-node attention dot products ----------------
__global__ __launch_bounds__(256) void k_dots(const float* __restrict__ xl, const float* __restrict__ a_s,
    const float* __restrict__ a_d, float* __restrict__ asrc, float* __restrict__ adst){
  int w = threadIdx.x >> 6, lane = threadIdx.x & 63;
  int n = blockIdx.x*WPB + w;
  float x0 = xl[(size_t)n*128+lane], x1 = xl[(size_t)n*128+64+lane];
  float s = x0*a_s[lane] + x1*a_s[64+lane];
  float d = x0*a_d[lane] + x1*a_d[64+lane];
  for (int off=32; off; off>>=1){ s += __shfl_xor(s,off); d += __shfl_xor(d,off); }
  if (lane==0){ asrc[n]=s; adst[n]=d; }
}

// ---------------- wea = We @ a_e (16 outputs, tiny) ----------------
__global__ __launch_bounds__(64) void k_wea(const float* __restrict__ We, const float* __restrict__ ae,
    float* __restrict__ wea){
  int t = threadIdx.x;
  if (t < 16){
    float acc = 0.f;
    for (int j=0;j<128;j++) acc += We[t*128+j]*ae[j];
    wea[t]=acc;
  }
}

// ---------------- per-row dot16 with wea (used for edges and node self-loop attrs) ----------------
__global__ __launch_bounds__(256) void k_dot16(const float* __restrict__ ea, const float* __restrict__ wea,
    float* __restrict__ out, int count){
  int e = blockIdx.x*256+threadIdx.x;
  if (e >= count) return;
  const float4* w4 = (const float4*)wea;
  float4 w0=w4[0], w1=w4[1], w2=w4[2], w3=w4[3];
  const float4* p = (const float4*)(ea + (size_t)e*16);
  float4 a0=p[0], a1=p[1], a2=p[2], a3=p[3];
  out[e] = a0.x*w0.x+a0.y*w0.y+a0.z*w0.z+a0.w*w0.w
         + a1.x*w1.x+a1.y*w1.y+a1.z*w1.z+a1.w*w1.w
         + a2.x*w2.x+a2.y*w2.y+a2.z*w2.z+a2.w*w2.w
         + a3.x*w3.x+a3.y*w3.y+a3.z*w3.z+a3.w*w3.w;
}

// ---------------- GAT aggregation: wave per node, softmax over in-edges + self loop ----------------
__global__ __launch_bounds__(256) void k_agg(const int* __restrict__ rowptr, const int* __restrict__ csr_src,
    const int* __restrict__ csr_eid, const float* __restrict__ aedge, const float* __restrict__ asrc,
    const float* __restrict__ adst, const float* __restrict__ aloop, const float* __restrict__ xl,
    const float* __restrict__ bias, float* __restrict__ out, int relu){
  int w = threadIdx.x >> 6;
  int lane = threadIdx.x & 63;
  int n = blockIdx.x * WPB + w;          // grid exact
  __shared__ float wbuf[WPB][MAXDEG];
  __shared__ int   sbuf[WPB][MAXDEG];
  int s0 = rowptr[n], s1 = rowptr[n+1];
  int deg = s1 - s0;
  float adst_n = adst[n];
  float al = lrelu(asrc[n] + adst_n + aloop[n]);   // self-loop alpha
  // pass A: alphas (lane-parallel), running max
  float m = al;
  for (int base=0; base<deg; base+=64){
    int i = base + lane;
    float a = -1e30f;
    if (i < deg){
      int e = s0 + i;
      int sx = csr_src[e];
      float av = lrelu(asrc[sx] + adst_n + aedge[csr_eid[e]]);
      if (i < MAXDEG){ wbuf[w][i] = av; sbuf[w][i] = sx; }
      a = av;
    }
    for (int off=32; off; off>>=1) a = fmaxf(a, __shfl_xor(a, off));
    m = fmaxf(m, a);
  }
  // pass B: exp + sum (same-lane LDS reuse)
  float p = 0.f;
  for (int i=lane; i<deg; i+=64){
    float av;
    if (i < MAXDEG) av = wbuf[w][i];
    else { int e = s0+i; av = lrelu(asrc[csr_src[e]] + adst_n + aedge[csr_eid[e]]); }
    float ev = __expf(av - m);
    if (i < MAXDEG) wbuf[w][i] = ev;
    p += ev;
  }
  for (int off=32; off; off>>=1) p += __shfl_xor(p, off);
  float wl = __expf(al - m);
  float denom = p + wl;
  __syncthreads();   // cross-lane LDS visibility for pass C (uniform: once per thread)
  // pass C: weighted gather of xl rows
  float acc0 = wl * xl[(size_t)n*128 + lane];
  float acc1 = wl * xl[(size_t)n*128 + 64 + lane];
  for (int i=0; i<deg; i++){
    int sx; float we;
    if (i < MAXDEG){ sx = sbuf[w][i]; we = wbuf[w][i]; }
    else {
      int e = s0+i; sx = csr_src[e];
      we = __expf(lrelu(asrc[sx] + adst_n + aedge[csr_eid[e]]) - m);
    }
    const float* row = xl + (size_t)sx*128;
    acc0 += we * row[lane];
    acc1 += we * row[lane+64];
  }
  float inv = 1.f/denom;
  float o0 = acc0*inv + bias[lane];
  float o1 = acc1*inv + bias[lane+64];
  if (relu){ o0 = fmaxf(o0,0.f); o1 = fmaxf(o1,0.f); }
  out[(size_t)n*128 + lane] = o0;
  out[(size_t)n*128 + 64 + lane] = o1;
}

// ---------------- lin2 (128->16) + log_softmax, wave per node ----------------
__global__ __launch_bounds__(256) void k_lin2(const float* __restrict__ h, const float* __restrict__ w2,
    const float* __restrict__ b2, float* __restrict__ out){
  int w = threadIdx.x >> 6, lane = threadIdx.x & 63;
  int n = blockIdx.x * WPB + w;
  __shared__ float lg[WPB][16];
  float h0 = h[(size_t)n*128+lane], h1 = h[(size_t)n*128+64+lane];
  #pragma unroll
  for (int c=0;c<16;c++){
    float p = h0*w2[lane*16+c] + h1*w2[(lane+64)*16+c];
    for (int off=32; off; off>>=1) p += __shfl_xor(p, off);
    if (lane==0) lg[w][c] = p + b2[c];
  }
  __syncthreads();
  if (lane < 16){
    float mx = -1e30f;
    #pragma unroll
    for (int c=0;c<16;c++) mx = fmaxf(mx, lg[w][c]);
    float se = 0.f;
    #pragma unroll
    for (int c=0;c<16;c++) se += __expf(lg[w][c]-mx);
    out[(size_t)n*16+lane] = lg[w][lane] - mx - __logf(se);
  }
}

extern "C" void kernel_launch(void* const* d_in, const int* in_sizes, int n_in,
                              void* d_out, int out_size, void* d_ws, size_t ws_size,
                              hipStream_t stream){
  const float* x    = (const float*)d_in[0];
  const float* eatt = (const float*)d_in[1];
  const float* W0   = (const float*)d_in[2];
  const float* as0  = (const float*)d_in[3];
  const float* ad0  = (const float*)d_in[4];
  const float* We0  = (const float*)d_in[5];
  const float* ae0  = (const float*)d_in[6];
  const float* b0   = (const float*)d_in[7];
  const float* W1   = (const float*)d_in[8];
  const float* as1  = (const float*)d_in[9];
  const float* ad1  = (const float*)d_in[10];
  const float* We1  = (const float*)d_in[11];
  const float* ae1  = (const float*)d_in[12];
  const float* b1   = (const float*)d_in[13];
  const float* l1w  = (const float*)d_in[14];
  const float* l1b  = (const float*)d_in[15];
  const float* l2w  = (const float*)d_in[16];
  const float* l2b  = (const float*)d_in[17];
  const int*   ei   = (const int*)d_in[18];
  const int* srcI = ei;
  const int* dstI = ei + N_EDGES;
  float* out = (float*)d_out;

  char* p = (char*)d_ws;
  auto alloc = [&](size_t bytes)->char*{ char* r = p; p += (bytes + 255) & ~255ull; return r; };
  float* A       = (float*)alloc((size_t)N_NODES*128*4);
  float* B       = (float*)alloc((size_t)N_NODES*128*4);
  float* ea_mean = (float*)alloc((size_t)N_NODES*16*4);
  float* aedge   = (float*)alloc((size_t)N_EDGES*4);
  float* asrc    = (float*)alloc((size_t)N_NODES*4);
  float* adst    = (float*)alloc((size_t)N_NODES*4);
  float* aloop   = (float*)alloc((size_t)N_NODES*4);
  float* wea     = (float*)alloc(64);
  int* deg     = (int*)alloc((size_t)N_NODES*4);
  int* fill    = (int*)alloc((size_t)N_NODES*4);
  int* rowptr  = (int*)alloc((size_t)(N_NODES+1)*4);
  int* csr_src = (int*)alloc((size_t)N_EDGES*4);
  int* csr_eid = (int*)alloc((size_t)N_EDGES*4);
  int* incl    = (int*)alloc((size_t)N_NODES*4);
  int* bsum    = (int*)alloc(512*4);
  int* bexcl   = (int*)alloc(512*4);

  const int NB_E = (N_EDGES+255)/256;   // 6250
  const int NB_N = (N_NODES+255)/256;   // 391
  const int NB_W = N_NODES/WPB;         // 25000 (exact)
  const int NB_G = (N_NODES+63)/64;     // 1563

  // ---- shared preprocessing ----
  // NOTE: deg and fill are SEPARATE allocations with 256B-rounded padding
  // between them (N_NODES*4 = 400000 is NOT 256-aligned). Memset each with
  // its exact size — a fused memset left 32 poisoned fill counters last
  // round -> atomicAdd returned ~2.8e9 -> OOB csr write -> core dump.
  hipMemsetAsync(deg,  0, (size_t)N_NODES*4, stream);
  hipMemsetAsync(fill, 0, (size_t)N_NODES*4, stream);
  k_deg   <<<NB_E,256,0,stream>>>(dstI, deg);
  k_scan_a<<<NB_N,256,0,stream>>>(deg, incl, bsum);
  k_scan_b<<<1,  512,0,stream>>>(bsum, bexcl, NB_N);
  k_scan_c<<<NB_N,256,0,stream>>>(incl, deg, bexcl, rowptr);
  k_fill  <<<NB_E,256,0,stream>>>(srcI, dstI, rowptr, fill, csr_src, csr_eid);
  k_eamean<<<NB_W,256,0,stream>>>(rowptr, csr_eid, eatt, ea_mean);

  // ---- layer 0 ----
  k_gemm <<<NB_G,256,0,stream>>>(x, W0, nullptr, A, N_NODES, 0);
  k_dots <<<NB_W,256,0,stream>>>(A, as0, ad0, asrc, adst);
  k_wea  <<<1,   64,0,stream>>>(We0, ae0, wea);
  k_dot16<<<NB_E,256,0,stream>>>(eatt, wea, aedge, N_EDGES);
  k_dot16<<<NB_N,256,0,stream>>>(ea_mean, wea, aloop, N_NODES);
  k_agg  <<<NB_W,256,0,stream>>>(rowptr, csr_src, csr_eid, aedge, asrc, adst, aloop, A, b0, B, 1);

  // ---- layer 1 ----
  k_gemm <<<NB_G,256,0,stream>>>(B, W1, nullptr, A, N_NODES, 0);
  k_dots <<<NB_W,256,0,stream>>>(A, as1, ad1, asrc, adst);
  k_wea  <<<1,   64,0,stream>>>(We1, ae1, wea);
  k_dot16<<<NB_E,256,0,stream>>>(eatt, wea, aedge, N_EDGES);
  k_dot16<<<NB_N,256,0,stream>>>(ea_mean, wea, aloop, N_NODES);
  k_agg  <<<NB_W,256,0,stream>>>(rowptr, csr_src, csr_eid, aedge, asrc, adst, aloop, A, b1, B, 1);

  // ---- post MLP ----
  k_gemm <<<NB_G,256,0,stream>>>(B, l1w, l1b, A, N_NODES, 1);
  k_lin2 <<<NB_W,256,0,stream>>>(A, l2w, l2b, out);
}

// Round 3
// 1045.486 us; speedup vs baseline: 1.2994x; 1.2994x over previous
//
#include <hip/hip_runtime.h>
#include <math.h>

#define N_NODES 100000
#define N_EDGES 1600000
#define NEG 0.2f
#define MAXDEG 128
#define WPB 4   // waves per block for per-node kernels

__device__ __forceinline__ float lrelu(float x){ return x > 0.f ? x : NEG*x; }

// ---------------- degree count ----------------
__global__ __launch_bounds__(256) void k_deg(const int* __restrict__ dst, int* __restrict__ deg){
  int e = blockIdx.x*256 + threadIdx.x;
  if (e < N_EDGES) atomicAdd(&deg[dst[e]], 1);
}

// ---------------- exclusive scan (3 phase) ----------------
__global__ __launch_bounds__(256) void k_scan_a(const int* __restrict__ deg, int* __restrict__ incl, int* __restrict__ bsum){
  __shared__ int s[256];
  int t = threadIdx.x; int i = blockIdx.x*256 + t;
  int v = (i < N_NODES) ? deg[i] : 0;
  s[t] = v; __syncthreads();
  for (int off=1; off<256; off<<=1){
    int u = (t>=off)? s[t-off] : 0; __syncthreads();
    s[t] += u; __syncthreads();
  }
  if (i < N_NODES) incl[i] = s[t];
  if (t == 255) bsum[blockIdx.x] = s[t];
}
__global__ __launch_bounds__(512) void k_scan_b(const int* __restrict__ bsum, int* __restrict__ bexcl, int nb){
  __shared__ int s[512];
  int t = threadIdx.x;
  int v = (t<nb)? bsum[t] : 0;
  s[t] = v; __syncthreads();
  for (int off=1; off<512; off<<=1){
    int u = (t>=off)? s[t-off] : 0; __syncthreads();
    s[t] += u; __syncthreads();
  }
  if (t<nb) bexcl[t] = s[t]-v;
}
__global__ __launch_bounds__(256) void k_scan_c(const int* __restrict__ incl, const int* __restrict__ deg,
    const int* __restrict__ bexcl, int* __restrict__ rowptr){
  int i = blockIdx.x*256+threadIdx.x;
  if (i < N_NODES) rowptr[i] = incl[i] - deg[i] + bexcl[blockIdx.x];
  if (i == 0) rowptr[N_NODES] = N_EDGES;
}

// ---------------- CSR fill ----------------
__global__ __launch_bounds__(256) void k_fill(const int* __restrict__ src, const int* __restrict__ dst,
     const int* __restrict__ rowptr, int* __restrict__ fill, int* __restrict__ csr_src, int* __restrict__ csr_eid){
  int e = blockIdx.x*256+threadIdx.x;
  if (e >= N_EDGES) return;
  int d = dst[e];
  int p = rowptr[d] + atomicAdd(&fill[d], 1);
  csr_src[p] = src[e];
  csr_eid[p] = e;
}

// ---------------- per-node mean of incoming edge_attr ----------------
__global__ __launch_bounds__(256) void k_eamean(const int* __restrict__ rowptr, const int* __restrict__ csr_eid,
    const float* __restrict__ ea, float* __restrict__ ea_mean){
  int w = threadIdx.x >> 6, lane = threadIdx.x & 63;
  int n = blockIdx.x * WPB + w;          // grid is exact: n < N_NODES always
  int j = lane & 15, g = lane >> 4;
  int s0 = rowptr[n]; int deg = rowptr[n+1]-s0;
  float acc = 0.f;
  for (int i=g; i<deg; i+=4) acc += ea[(size_t)csr_eid[s0+i]*16 + j];
  acc += __shfl_xor(acc, 16);
  acc += __shfl_xor(acc, 32);
  if (lane < 16) ea_mean[n*16 + j] = acc / fmaxf((float)deg, 1.f);
}

// ---------------- fp32 GEMM: Y[M,128] = X[M,128] @ W[128,128] (+bias,relu) ----------------
__global__ __launch_bounds__(256) void k_gemm(const float* __restrict__ X, const float* __restrict__ W,
    const float* __restrict__ bias, float* __restrict__ Y, int M, int relu){
  __shared__ float Xs[16][68];     // [kk][row], pad 68 keeps float4 reads aligned, conflicts <= 2-way
  __shared__ float Ws[16][128];
  int t = threadIdx.x;
  int row0 = blockIdx.x * 64;
  int tc = t & 15, tr = t >> 4;
  int c0 = tc*8, r0 = tr*4;
  int lr = t >> 2, lc = (t & 3) << 2; // X staging: row lr, 4 cols at lc
  int wk = t >> 4, wc = (t & 15) * 8; // W staging
  float acc[4][8];
  #pragma unroll
  for (int i=0;i<4;i++)
    #pragma unroll
    for (int j=0;j<8;j++) acc[i][j]=0.f;
  int gr = row0 + lr;
  for (int k0=0; k0<128; k0+=16){
    float4 xv = make_float4(0.f,0.f,0.f,0.f);
    if (gr < M) xv = *(const float4*)(X + (size_t)gr*128 + k0 + lc);
    float4 wv0 = *(const float4*)(W + (size_t)(k0+wk)*128 + wc);
    float4 wv1 = *(const float4*)(W + (size_t)(k0+wk)*128 + wc + 4);
    __syncthreads();
    Xs[lc+0][lr]=xv.x; Xs[lc+1][lr]=xv.y; Xs[lc+2][lr]=xv.z; Xs[lc+3][lr]=xv.w;
    *(float4*)&Ws[wk][wc]   = wv0;
    *(float4*)&Ws[wk][wc+4] = wv1;
    __syncthreads();
    #pragma unroll
    for (int kk=0;kk<16;kk++){
      float4 a  = *(const float4*)&Xs[kk][r0];
      float4 b0 = *(const float4*)&Ws[kk][c0];
      float4 b1 = *(const float4*)&Ws[kk][c0+4];
      float av[4] = {a.x,a.y,a.z,a.w};
      float bv[8] = {b0.x,b0.y,b0.z,b0.w,b1.x,b1.y,b1.z,b1.w};
      #pragma unroll
      for (int i=0;i<4;i++)
        #pragma unroll
        for (int j=0;j<8;j++) acc[i][j] += av[i]*bv[j];
    }
  }
  #pragma unroll
  for (int i=0;i<4;i++){
    int r = row0 + r0 + i;
    if (r < M){
      #pragma unroll
      for (int j=0;j<8;j++){
        float v = acc[i][j] + (bias ? bias[c0+j] : 0.f);
        if (relu) v = fmaxf(v, 0.f);
        Y[(size_t)r*128 + c0 + j] = v;
      }
    }
  }
}

// ---------------- per-node attention dot products ----------------
__global__ __launch_bounds__(256) void k_dots(const float* __restrict__ xl, const float* __restrict__ a_s,
    const float* __restrict__ a_d, float* __restrict__ asrc, float* __restrict__ adst){
  int w = threadIdx.x >> 6, lane = threadIdx.x & 63;
  int n = blockIdx.x*WPB + w;
  float x0 = xl[(size_t)n*128+lane], x1 = xl[(size_t)n*128+64+lane];
  float s = x0*a_s[lane] + x1*a_s[64+lane];
  float d = x0*a_d[lane] + x1*a_d[64+lane];
  for (int off=32; off; off>>=1){ s += __shfl_xor(s,off); d += __shfl_xor(d,off); }
  if (lane==0){ asrc[n]=s; adst[n]=d; }
}

// ---------------- wea = We @ a_e (16 outputs, tiny) ----------------
__global__ __launch_bounds__(64) void k_wea(const float* __restrict__ We, const float* __restrict__ ae,
    float* __restrict__ wea){
  int t = threadIdx.x;
  if (t < 16){
    float acc = 0.f;
    for (int j=0;j<128;j++) acc += We[t*128+j]*ae[j];
    wea[t]=acc;
  }
}

// ---------------- per-row dot16 with wea (used for edges and node self-loop attrs) ----------------
__global__ __launch_bounds__(256) void k_dot16(const float* __restrict__ ea, const float* __restrict__ wea,
    float* __restrict__ out, int count){
  int e = blockIdx.x*256+threadIdx.x;
  if (e >= count) return;
  const float4* w4 = (const float4*)wea;
  float4 w0=w4[0], w1=w4[1], w2=w4[2], w3=w4[3];
  const float4* p = (const float4*)(ea + (size_t)e*16);
  float4 a0=p[0], a1=p[1], a2=p[2], a3=p[3];
  out[e] = a0.x*w0.x+a0.y*w0.y+a0.z*w0.z+a0.w*w0.w
         + a1.x*w1.x+a1.y*w1.y+a1.z*w1.z+a1.w*w1.w
         + a2.x*w2.x+a2.y*w2.y+a2.z*w2.z+a2.w*w2.w
         + a3.x*w3.x+a3.y*w3.y+a3.z*w3.z+a3.w*w3.w;
}

// ---------------- GAT aggregation: wave per node, softmax over in-edges + self loop ----------------
__global__ __launch_bounds__(256) void k_agg(const int* __restrict__ rowptr, const int* __restrict__ csr_src,
    const int* __restrict__ csr_eid, const float* __restrict__ aedge, const float* __restrict__ asrc,
    const float* __restrict__ adst, const float* __restrict__ aloop, const float* __restrict__ xl,
    const float* __restrict__ bias, float* __restrict__ out, int relu){
  int w = threadIdx.x >> 6;
  int lane = threadIdx.x & 63;
  int n = blockIdx.x * WPB + w;          // grid exact
  __shared__ float wbuf[WPB][MAXDEG];
  __shared__ int   sbuf[WPB][MAXDEG];
  int s0 = rowptr[n], s1 = rowptr[n+1];
  int deg = s1 - s0;
  float adst_n = adst[n];
  float al = lrelu(asrc[n] + adst_n + aloop[n]);   // self-loop alpha
  // pass A: alphas (lane-parallel), running max
  float m = al;
  for (int base=0; base<deg; base+=64){
    int i = base + lane;
    float a = -1e30f;
    if (i < deg){
      int e = s0 + i;
      int sx = csr_src[e];
      float av = lrelu(asrc[sx] + adst_n + aedge[csr_eid[e]]);
      if (i < MAXDEG){ wbuf[w][i] = av; sbuf[w][i] = sx; }
      a = av;
    }
    for (int off=32; off; off>>=1) a = fmaxf(a, __shfl_xor(a, off));
    m = fmaxf(m, a);
  }
  // pass B: exp + sum (same-lane LDS reuse)
  float p = 0.f;
  for (int i=lane; i<deg; i+=64){
    float av;
    if (i < MAXDEG) av = wbuf[w][i];
    else { int e = s0+i; av = lrelu(asrc[csr_src[e]] + adst_n + aedge[csr_eid[e]]); }
    float ev = __expf(av - m);
    if (i < MAXDEG) wbuf[w][i] = ev;
    p += ev;
  }
  for (int off=32; off; off>>=1) p += __shfl_xor(p, off);
  float wl = __expf(al - m);
  float denom = p + wl;
  __syncthreads();   // cross-lane LDS visibility for pass C (uniform: once per thread)
  // pass C: weighted gather of xl rows
  float acc0 = wl * xl[(size_t)n*128 + lane];
  float acc1 = wl * xl[(size_t)n*128 + 64 + lane];
  for (int i=0; i<deg; i++){
    int sx; float we;
    if (i < MAXDEG){ sx = sbuf[w][i]; we = wbuf[w][i]; }
    else {
      int e = s0+i; sx = csr_src[e];
      we = __expf(lrelu(asrc[sx] + adst_n + aedge[csr_eid[e]]) - m);
    }
    const float* row = xl + (size_t)sx*128;
    acc0 += we * row[lane];
    acc1 += we * row[lane+64];
  }
  float inv = 1.f/denom;
  float o0 = acc0*inv + bias[lane];
  float o1 = acc1*inv + bias[lane+64];
  if (relu){ o0 = fmaxf(o0,0.f); o1 = fmaxf(o1,0.f); }
  out[(size_t)n*128 + lane] = o0;
  out[(size_t)n*128 + 64 + lane] = o1;
}

// ---------------- lin2 (128->16) + log_softmax ----------------
// R2 rewrite: old version was latency-bound on 96 dependent shuffles/wave
// (VALUBusy 14.7%, occupancy 91%, 357 us). Now: 64 nodes/block, thread owns
// (node t/4, classes (t%3)*4..+3), h tile staged in LDS with stride 132
// (bank = (4*nl+k)%32 -> max 2-way = free), w2 in LDS (quad-broadcast reads),
// log-softmax via 4 quad shuffles total.
__global__ __launch_bounds__(256) void k_lin2(const float* __restrict__ h, const float* __restrict__ w2,
    const float* __restrict__ b2, float* __restrict__ out){
  __shared__ float w2s[2048];
  __shared__ float b2s[16];
  __shared__ float hs[64*132];
  int t = threadIdx.x;
  int n0 = blockIdx.x * 64;
  // stage w2 (128x16) + b2
  #pragma unroll
  for (int i=0;i<2;i++) ((float4*)w2s)[t + i*256] = ((const float4*)w2)[t + i*256];
  if (t < 16) b2s[t] = b2[t];
  // stage h tile (coalesced float4), padded stride 132 floats
  int nmax = N_NODES - n0; if (nmax > 64) nmax = 64;
  for (int i=t; i < nmax*32; i += 256){
    int nl = i >> 5, c4 = i & 31;
    float4 v = *(const float4*)(h + (size_t)(n0+nl)*128 + c4*4);
    *(float4*)&hs[nl*132 + c4*4] = v;
  }
  __syncthreads();
  int nl = t >> 2, cq = (t & 3) * 4;
  int n = n0 + nl;
  if (n < N_NODES){
    float acc0=b2s[cq], acc1=b2s[cq+1], acc2=b2s[cq+2], acc3=b2s[cq+3];
    const float* hp = &hs[nl*132];
    #pragma unroll 8
    for (int k=0;k<128;k++){
      float hv = hp[k];
      float4 w4 = *(const float4*)&w2s[k*16 + cq];
      acc0 += hv*w4.x; acc1 += hv*w4.y; acc2 += hv*w4.z; acc3 += hv*w4.w;
    }
    // quad (lanes t, t^1, t^2 share node): 16-class max & sum-exp
    float m = fmaxf(fmaxf(acc0,acc1), fmaxf(acc2,acc3));
    m = fmaxf(m, __shfl_xor(m, 1));
    m = fmaxf(m, __shfl_xor(m, 2));
    float s = __expf(acc0-m)+__expf(acc1-m)+__expf(acc2-m)+__expf(acc3-m);
    s += __shfl_xor(s, 1);
    s += __shfl_xor(s, 2);
    float lse = m + __logf(s);
    float4 o = make_float4(acc0-lse, acc1-lse, acc2-lse, acc3-lse);
    *(float4*)(out + (size_t)n*16 + cq) = o;
  }
}

extern "C" void kernel_launch(void* const* d_in, const int* in_sizes, int n_in,
                              void* d_out, int out_size, void* d_ws, size_t ws_size,
                              hipStream_t stream){
  const float* x    = (const float*)d_in[0];
  const float* eatt = (const float*)d_in[1];
  const float* W0   = (const float*)d_in[2];
  const float* as0  = (const float*)d_in[3];
  const float* ad0  = (const float*)d_in[4];
  const float* We0  = (const float*)d_in[5];
  const float* ae0  = (const float*)d_in[6];
  const float* b0   = (const float*)d_in[7];
  const float* W1   = (const float*)d_in[8];
  const float* as1  = (const float*)d_in[9];
  const float* ad1  = (const float*)d_in[10];
  const float* We1  = (const float*)d_in[11];
  const float* ae1  = (const float*)d_in[12];
  const float* b1   = (const float*)d_in[13];
  const float* l1w  = (const float*)d_in[14];
  const float* l1b  = (const float*)d_in[15];
  const float* l2w  = (const float*)d_in[16];
  const float* l2b  = (const float*)d_in[17];
  const int*   ei   = (const int*)d_in[18];
  const int* srcI = ei;
  const int* dstI = ei + N_EDGES;
  float* out = (float*)d_out;

  char* p = (char*)d_ws;
  auto alloc = [&](size_t bytes)->char*{ char* r = p; p += (bytes + 255) & ~255ull; return r; };
  float* A       = (float*)alloc((size_t)N_NODES*128*4);
  float* B       = (float*)alloc((size_t)N_NODES*128*4);
  float* ea_mean = (float*)alloc((size_t)N_NODES*16*4);
  float* aedge   = (float*)alloc((size_t)N_EDGES*4);
  float* asrc    = (float*)alloc((size_t)N_NODES*4);
  float* adst    = (float*)alloc((size_t)N_NODES*4);
  float* aloop   = (float*)alloc((size_t)N_NODES*4);
  float* wea     = (float*)alloc(64);
  int* deg     = (int*)alloc((size_t)N_NODES*4);
  int* fill    = (int*)alloc((size_t)N_NODES*4);
  int* rowptr  = (int*)alloc((size_t)(N_NODES+1)*4);
  int* csr_src = (int*)alloc((size_t)N_EDGES*4);
  int* csr_eid = (int*)alloc((size_t)N_EDGES*4);
  int* incl    = (int*)alloc((size_t)N_NODES*4);
  int* bsum    = (int*)alloc(512*4);
  int* bexcl   = (int*)alloc(512*4);

  const int NB_E = (N_EDGES+255)/256;   // 6250
  const int NB_N = (N_NODES+255)/256;   // 391
  const int NB_W = N_NODES/WPB;         // 25000 (exact)
  const int NB_G = (N_NODES+63)/64;     // 1563

  // ---- shared preprocessing ----
  // deg/fill memset: exact sizes, allocations are 256B-padded apart.
  hipMemsetAsync(deg,  0, (size_t)N_NODES*4, stream);
  hipMemsetAsync(fill, 0, (size_t)N_NODES*4, stream);
  k_deg   <<<NB_E,256,0,stream>>>(dstI, deg);
  k_scan_a<<<NB_N,256,0,stream>>>(deg, incl, bsum);
  k_scan_b<<<1,  512,0,stream>>>(bsum, bexcl, NB_N);
  k_scan_c<<<NB_N,256,0,stream>>>(incl, deg, bexcl, rowptr);
  k_fill  <<<NB_E,256,0,stream>>>(srcI, dstI, rowptr, fill, csr_src, csr_eid);
  k_eamean<<<NB_W,256,0,stream>>>(rowptr, csr_eid, eatt, ea_mean);

  // ---- layer 0 ----
  k_gemm <<<NB_G,256,0,stream>>>(x, W0, nullptr, A, N_NODES, 0);
  k_dots <<<NB_W,256,0,stream>>>(A, as0, ad0, asrc, adst);
  k_wea  <<<1,   64,0,stream>>>(We0, ae0, wea);
  k_dot16<<<NB_E,256,0,stream>>>(eatt, wea, aedge, N_EDGES);
  k_dot16<<<NB_N,256,0,stream>>>(ea_mean, wea, aloop, N_NODES);
  k_agg  <<<NB_W,256,0,stream>>>(rowptr, csr_src, csr_eid, aedge, asrc, adst, aloop, A, b0, B, 1);

  // ---- layer 1 ----
  k_gemm <<<NB_G,256,0,stream>>>(B, W1, nullptr, A, N_NODES, 0);
  k_dots <<<NB_W,256,0,stream>>>(A, as1, ad1, asrc, adst);
  k_wea  <<<1,   64,0,stream>>>(We1, ae1, wea);
  k_dot16<<<NB_E,256,0,stream>>>(eatt, wea, aedge, N_EDGES);
  k_dot16<<<NB_N,256,0,stream>>>(ea_mean, wea, aloop, N_NODES);
  k_agg  <<<NB_W,256,0,stream>>>(rowptr, csr_src, csr_eid, aedge, asrc, adst, aloop, A, b1, B, 1);

  // ---- post MLP ----
  k_gemm <<<NB_G,256,0,stream>>>(B, l1w, l1b, A, N_NODES, 1);
  k_lin2 <<<NB_W,256,0,stream>>>(A, l2w, l2b, out);
}

// Round 4
// 906.429 us; speedup vs baseline: 1.4987x; 1.1534x over previous
//
#include <hip/hip_runtime.h>
#include <math.h>

#define N_NODES 100000
#define N_EDGES 1600000
#define NEG 0.2f
#define MAXDEG 128
#define WPB 4   // waves per block for per-node kernels

__device__ __forceinline__ float lrelu(float x){ return x > 0.f ? x : NEG*x; }
__device__ __forceinline__ unsigned short f2bf(float f){
  unsigned int u = __float_as_uint(f);
  u += 0x7FFFu + ((u >> 16) & 1u);   // RNE
  return (unsigned short)(u >> 16);
}

// ---------------- degree count ----------------
__global__ __launch_bounds__(256) void k_deg(const int* __restrict__ dst, int* __restrict__ deg){
  int e = blockIdx.x*256 + threadIdx.x;
  if (e < N_EDGES) atomicAdd(&deg[dst[e]], 1);
}

// ---------------- exclusive scan (3 phase) ----------------
__global__ __launch_bounds__(256) void k_scan_a(const int* __restrict__ deg, int* __restrict__ incl, int* __restrict__ bsum){
  __shared__ int s[256];
  int t = threadIdx.x; int i = blockIdx.x*256 + t;
  int v = (i < N_NODES) ? deg[i] : 0;
  s[t] = v; __syncthreads();
  for (int off=1; off<256; off<<=1){
    int u = (t>=off)? s[t-off] : 0; __syncthreads();
    s[t] += u; __syncthreads();
  }
  if (i < N_NODES) incl[i] = s[t];
  if (t == 255) bsum[blockIdx.x] = s[t];
}
__global__ __launch_bounds__(512) void k_scan_b(const int* __restrict__ bsum, int* __restrict__ bexcl, int nb){
  __shared__ int s[512];
  int t = threadIdx.x;
  int v = (t<nb)? bsum[t] : 0;
  s[t] = v; __syncthreads();
  for (int off=1; off<512; off<<=1){
    int u = (t>=off)? s[t-off] : 0; __syncthreads();
    s[t] += u; __syncthreads();
  }
  if (t<nb) bexcl[t] = s[t]-v;
}
__global__ __launch_bounds__(256) void k_scan_c(const int* __restrict__ incl, const int* __restrict__ deg,
    const int* __restrict__ bexcl, int* __restrict__ rowptr){
  int i = blockIdx.x*256+threadIdx.x;
  if (i < N_NODES) rowptr[i] = incl[i] - deg[i] + bexcl[blockIdx.x];
  if (i == 0) rowptr[N_NODES] = N_EDGES;
}

// ---------------- CSR fill ----------------
__global__ __launch_bounds__(256) void k_fill(const int* __restrict__ src, const int* __restrict__ dst,
     const int* __restrict__ rowptr, int* __restrict__ fill, int* __restrict__ csr_src, int* __restrict__ csr_eid){
  int e = blockIdx.x*256+threadIdx.x;
  if (e >= N_EDGES) return;
  int d = dst[e];
  int p = rowptr[d] + atomicAdd(&fill[d], 1);
  csr_src[p] = src[e];
  csr_eid[p] = e;
}

// ---------------- per-node mean of incoming edge_attr ----------------
__global__ __launch_bounds__(256) void k_eamean(const int* __restrict__ rowptr, const int* __restrict__ csr_eid,
    const float* __restrict__ ea, float* __restrict__ ea_mean){
  int w = threadIdx.x >> 6, lane = threadIdx.x & 63;
  int n = blockIdx.x * WPB + w;          // grid is exact: n < N_NODES always
  int j = lane & 15, g = lane >> 4;
  int s0 = rowptr[n]; int deg = rowptr[n+1]-s0;
  float acc = 0.f;
  for (int i=g; i<deg; i+=4) acc += ea[(size_t)csr_eid[s0+i]*16 + j];
  acc += __shfl_xor(acc, 16);
  acc += __shfl_xor(acc, 32);
  if (lane < 16) ea_mean[n*16 + j] = acc / fmaxf((float)deg, 1.f);
}

// ---------------- fp32 GEMM: Y[M,128] = X[M,128] @ W[128,128] (+bias,relu) ----------------
// R3: optional bf16 output (Ybf) fused into the epilogue; fp32 output (Y)
// optional — GAT layers write only bf16 (halves write traffic), lin1 only fp32.
__global__ __launch_bounds__(256) void k_gemm(const float* __restrict__ X, const float* __restrict__ W,
    const float* __restrict__ bias, float* __restrict__ Y, unsigned short* __restrict__ Ybf, int M, int relu){
  __shared__ float Xs[16][68];     // [kk][row], pad 68 keeps float4 reads aligned, conflicts <= 2-way
  __shared__ float Ws[16][128];
  int t = threadIdx.x;
  int row0 = blockIdx.x * 64;
  int tc = t & 15, tr = t >> 4;
  int c0 = tc*8, r0 = tr*4;
  int lr = t >> 2, lc = (t & 3) << 2; // X staging: row lr, 4 cols at lc
  int wk = t >> 4, wc = (t & 15) * 8; // W staging
  float acc[4][8];
  #pragma unroll
  for (int i=0;i<4;i++)
    #pragma unroll
    for (int j=0;j<8;j++) acc[i][j]=0.f;
  int gr = row0 + lr;
  for (int k0=0; k0<128; k0+=16){
    float4 xv = make_float4(0.f,0.f,0.f,0.f);
    if (gr < M) xv = *(const float4*)(X + (size_t)gr*128 + k0 + lc);
    float4 wv0 = *(const float4*)(W + (size_t)(k0+wk)*128 + wc);
    float4 wv1 = *(const float4*)(W + (size_t)(k0+wk)*128 + wc + 4);
    __syncthreads();
    Xs[lc+0][lr]=xv.x; Xs[lc+1][lr]=xv.y; Xs[lc+2][lr]=xv.z; Xs[lc+3][lr]=xv.w;
    *(float4*)&Ws[wk][wc]   = wv0;
    *(float4*)&Ws[wk][wc+4] = wv1;
    __syncthreads();
    #pragma unroll
    for (int kk=0;kk<16;kk++){
      float4 a  = *(const float4*)&Xs[kk][r0];
      float4 b0 = *(const float4*)&Ws[kk][c0];
      float4 b1 = *(const float4*)&Ws[kk][c0+4];
      float av[4] = {a.x,a.y,a.z,a.w};
      float bv[8] = {b0.x,b0.y,b0.z,b0.w,b1.x,b1.y,b1.z,b1.w};
      #pragma unroll
      for (int i=0;i<4;i++)
        #pragma unroll
        for (int j=0;j<8;j++) acc[i][j] += av[i]*bv[j];
    }
  }
  #pragma unroll
  for (int i=0;i<4;i++){
    int r = row0 + r0 + i;
    if (r < M){
      float v[8];
      #pragma unroll
      for (int j=0;j<8;j++){
        float u = acc[i][j] + (bias ? bias[c0+j] : 0.f);
        v[j] = relu ? fmaxf(u, 0.f) : u;
      }
      if (Y){
        *(float4*)(Y + (size_t)r*128 + c0)     = make_float4(v[0],v[1],v[2],v[3]);
        *(float4*)(Y + (size_t)r*128 + c0 + 4) = make_float4(v[4],v[5],v[6],v[7]);
      }
      if (Ybf){
        uint4 pk;
        pk.x = (unsigned)f2bf(v[0]) | ((unsigned)f2bf(v[1])<<16);
        pk.y = (unsigned)f2bf(v[2]) | ((unsigned)f2bf(v[3])<<16);
        pk.z = (unsigned)f2bf(v[4]) | ((unsigned)f2bf(v[5])<<16);
        pk.w = (unsigned)f2bf(v[6]) | ((unsigned)f2bf(v[7])<<16);
        *(uint4*)(Ybf + (size_t)r*128 + c0) = pk;
      }
    }
  }
}

// ---------------- per-node attention dot products (bf16 features) ----------------
__global__ __launch_bounds__(256) void k_dots(const unsigned short* __restrict__ xlbf, const float* __restrict__ a_s,
    const float* __restrict__ a_d, float* __restrict__ asrc, float* __restrict__ adst){
  int w = threadIdx.x >> 6, lane = threadIdx.x & 63;
  int n = blockIdx.x*WPB + w;
  unsigned int u = ((const unsigned int*)xlbf)[(size_t)n*64 + lane];
  float e0 = __uint_as_float(u << 16);
  float e1 = __uint_as_float(u & 0xFFFF0000u);
  float2 as2 = *(const float2*)(a_s + 2*lane);
  float2 ad2 = *(const float2*)(a_d + 2*lane);
  float s = e0*as2.x + e1*as2.y;
  float d = e0*ad2.x + e1*ad2.y;
  for (int off=32; off; off>>=1){ s += __shfl_xor(s,off); d += __shfl_xor(d,off); }
  if (lane==0){ asrc[n]=s; adst[n]=d; }
}

// ---------------- wea = We @ a_e (16 outputs, tiny) ----------------
__global__ __launch_bounds__(64) void k_wea(const float* __restrict__ We, const float* __restrict__ ae,
    float* __restrict__ wea){
  int t = threadIdx.x;
  if (t < 16){
    float acc = 0.f;
    for (int j=0;j<128;j++) acc += We[t*128+j]*ae[j];
    wea[t]=acc;
  }
}

// ---------------- per-row dot16 with wea (used for edges and node self-loop attrs) ----------------
__global__ __launch_bounds__(256) void k_dot16(const float* __restrict__ ea, const float* __restrict__ wea,
    float* __restrict__ out, int count){
  int e = blockIdx.x*256+threadIdx.x;
  if (e >= count) return;
  const float4* w4 = (const float4*)wea;
  float4 w0=w4[0], w1=w4[1], w2=w4[2], w3=w4[3];
  const float4* p = (const float4*)(ea + (size_t)e*16);
  float4 a0=p[0], a1=p[1], a2=p[2], a3=p[3];
  out[e] = a0.x*w0.x+a0.y*w0.y+a0.z*w0.z+a0.w*w0.w
         + a1.x*w1.x+a1.y*w1.y+a1.z*w1.z+a1.w*w1.w
         + a2.x*w2.x+a2.y*w2.y+a2.z*w2.z+a2.w*w2.w
         + a3.x*w3.x+a3.y*w3.y+a3.z*w3.z+a3.w*w3.w;
}

// ---------------- GAT aggregation: wave per node, softmax over in-edges + self loop ----------------
// R3: gathered features are bf16 — ONE uint load per lane covers the whole
// 128-wide row (2 elems/lane), halving both bytes and vmem instructions of
// the dominant random-gather stream. Accumulation stays fp32.
__global__ __launch_bounds__(256) void k_agg(const int* __restrict__ rowptr, const int* __restrict__ csr_src,
    const int* __restrict__ csr_eid, const float* __restrict__ aedge, const float* __restrict__ asrc,
    const float* __restrict__ adst, const float* __restrict__ aloop, const unsigned short* __restrict__ xlbf,
    const float* __restrict__ bias, float* __restrict__ out, int relu){
  int w = threadIdx.x >> 6;
  int lane = threadIdx.x & 63;
  int n = blockIdx.x * WPB + w;          // grid exact
  __shared__ float wbuf[WPB][MAXDEG];
  __shared__ int   sbuf[WPB][MAXDEG];
  const unsigned int* xb = (const unsigned int*)xlbf;  // row = 64 uints
  int s0 = rowptr[n], s1 = rowptr[n+1];
  int deg = s1 - s0;
  float adst_n = adst[n];
  float al = lrelu(asrc[n] + adst_n + aloop[n]);   // self-loop alpha
  // pass A: alphas (lane-parallel), running max
  float m = al;
  for (int base=0; base<deg; base+=64){
    int i = base + lane;
    float a = -1e30f;
    if (i < deg){
      int e = s0 + i;
      int sx = csr_src[e];
      float av = lrelu(asrc[sx] + adst_n + aedge[csr_eid[e]]);
      if (i < MAXDEG){ wbuf[w][i] = av; sbuf[w][i] = sx; }
      a = av;
    }
    for (int off=32; off; off>>=1) a = fmaxf(a, __shfl_xor(a, off));
    m = fmaxf(m, a);
  }
  // pass B: exp + sum (same-lane LDS reuse)
  float p = 0.f;
  for (int i=lane; i<deg; i+=64){
    float av;
    if (i < MAXDEG) av = wbuf[w][i];
    else { int e = s0+i; av = lrelu(asrc[csr_src[e]] + adst_n + aedge[csr_eid[e]]); }
    float ev = __expf(av - m);
    if (i < MAXDEG) wbuf[w][i] = ev;
    p += ev;
  }
  for (int off=32; off; off>>=1) p += __shfl_xor(p, off);
  float wl = __expf(al - m);
  float denom = p + wl;
  __syncthreads();   // cross-lane LDS visibility for pass C (uniform: once per thread)
  // pass C: weighted gather of bf16 rows
  unsigned int su = xb[(size_t)n*64 + lane];
  float acc0 = wl * __uint_as_float(su << 16);
  float acc1 = wl * __uint_as_float(su & 0xFFFF0000u);
  for (int i=0; i<deg; i++){
    int sx; float we;
    if (i < MAXDEG){ sx = sbuf[w][i]; we = wbuf[w][i]; }
    else {
      int e = s0+i; sx = csr_src[e];
      we = __expf(lrelu(asrc[sx] + adst_n + aedge[csr_eid[e]]) - m);
    }
    unsigned int v = xb[(size_t)sx*64 + lane];
    acc0 += we * __uint_as_float(v << 16);
    acc1 += we * __uint_as_float(v & 0xFFFF0000u);
  }
  float inv = 1.f/denom;
  float2 bv = *(const float2*)(bias + 2*lane);
  float o0 = acc0*inv + bv.x;
  float o1 = acc1*inv + bv.y;
  if (relu){ o0 = fmaxf(o0,0.f); o1 = fmaxf(o1,0.f); }
  *(float2*)(out + (size_t)n*128 + 2*lane) = make_float2(o0, o1);
}

// ---------------- lin2 (128->16) + log_softmax ----------------
// R2 rewrite: 64 nodes/block, thread owns (node t/4, classes (t%4)*4..+3),
// h tile staged in LDS stride 132 (max 2-way bank alias = free), w2 in LDS,
// log-softmax via 4 quad shuffles total.
__global__ __launch_bounds__(256) void k_lin2(const float* __restrict__ h, const float* __restrict__ w2,
    const float* __restrict__ b2, float* __restrict__ out){
  __shared__ float w2s[2048];
  __shared__ float b2s[16];
  __shared__ float hs[64*132];
  int t = threadIdx.x;
  int n0 = blockIdx.x * 64;
  #pragma unroll
  for (int i=0;i<2;i++) ((float4*)w2s)[t + i*256] = ((const float4*)w2)[t + i*256];
  if (t < 16) b2s[t] = b2[t];
  int nmax = N_NODES - n0; if (nmax > 64) nmax = 64;
  for (int i=t; i < nmax*32; i += 256){
    int nl = i >> 5, c4 = i & 31;
    float4 v = *(const float4*)(h + (size_t)(n0+nl)*128 + c4*4);
    *(float4*)&hs[nl*132 + c4*4] = v;
  }
  __syncthreads();
  int nl = t >> 2, cq = (t & 3) * 4;
  int n = n0 + nl;
  if (n < N_NODES){
    float acc0=b2s[cq], acc1=b2s[cq+1], acc2=b2s[cq+2], acc3=b2s[cq+3];
    const float* hp = &hs[nl*132];
    #pragma unroll 8
    for (int k=0;k<128;k++){
      float hv = hp[k];
      float4 w4 = *(const float4*)&w2s[k*16 + cq];
      acc0 += hv*w4.x; acc1 += hv*w4.y; acc2 += hv*w4.z; acc3 += hv*w4.w;
    }
    float m = fmaxf(fmaxf(acc0,acc1), fmaxf(acc2,acc3));
    m = fmaxf(m, __shfl_xor(m, 1));
    m = fmaxf(m, __shfl_xor(m, 2));
    float s = __expf(acc0-m)+__expf(acc1-m)+__expf(acc2-m)+__expf(acc3-m);
    s += __shfl_xor(s, 1);
    s += __shfl_xor(s, 2);
    float lse = m + __logf(s);
    float4 o = make_float4(acc0-lse, acc1-lse, acc2-lse, acc3-lse);
    *(float4*)(out + (size_t)n*16 + cq) = o;
  }
}

extern "C" void kernel_launch(void* const* d_in, const int* in_sizes, int n_in,
                              void* d_out, int out_size, void* d_ws, size_t ws_size,
                              hipStream_t stream){
  const float* x    = (const float*)d_in[0];
  const float* eatt = (const float*)d_in[1];
  const float* W0   = (const float*)d_in[2];
  const float* as0  = (const float*)d_in[3];
  const float* ad0  = (const float*)d_in[4];
  const float* We0  = (const float*)d_in[5];
  const float* ae0  = (const float*)d_in[6];
  const float* b0   = (const float*)d_in[7];
  const float* W1   = (const float*)d_in[8];
  const float* as1  = (const float*)d_in[9];
  const float* ad1  = (const float*)d_in[10];
  const float* We1  = (const float*)d_in[11];
  const float* ae1  = (const float*)d_in[12];
  const float* b1   = (const float*)d_in[13];
  const float* l1w  = (const float*)d_in[14];
  const float* l1b  = (const float*)d_in[15];
  const float* l2w  = (const float*)d_in[16];
  const float* l2b  = (const float*)d_in[17];
  const int*   ei   = (const int*)d_in[18];
  const int* srcI = ei;
  const int* dstI = ei + N_EDGES;
  float* out = (float*)d_out;

  char* p = (char*)d_ws;
  auto alloc = [&](size_t bytes)->char*{ char* r = p; p += (bytes + 255) & ~255ull; return r; };
  float* A       = (float*)alloc((size_t)N_NODES*128*4);   // fp32 features (lin1 out)
  unsigned short* Abf = (unsigned short*)alloc((size_t)N_NODES*128*2); // bf16 features (GAT layers)
  float* B       = (float*)alloc((size_t)N_NODES*128*4);   // aggregation output
  float* ea_mean = (float*)alloc((size_t)N_NODES*16*4);
  float* aedge   = (float*)alloc((size_t)N_EDGES*4);
  float* asrc    = (float*)alloc((size_t)N_NODES*4);
  float* adst    = (float*)alloc((size_t)N_NODES*4);
  float* aloop   = (float*)alloc((size_t)N_NODES*4);
  float* wea     = (float*)alloc(64);
  int* deg     = (int*)alloc((size_t)N_NODES*4);
  int* fill    = (int*)alloc((size_t)N_NODES*4);
  int* rowptr  = (int*)alloc((size_t)(N_NODES+1)*4);
  int* csr_src = (int*)alloc((size_t)N_EDGES*4);
  int* csr_eid = (int*)alloc((size_t)N_EDGES*4);
  int* incl    = (int*)alloc((size_t)N_NODES*4);
  int* bsum    = (int*)alloc(512*4);
  int* bexcl   = (int*)alloc(512*4);

  const int NB_E = (N_EDGES+255)/256;   // 6250
  const int NB_N = (N_NODES+255)/256;   // 391
  const int NB_W = N_NODES/WPB;         // 25000 (exact)
  const int NB_G = (N_NODES+63)/64;     // 1563

  // ---- shared preprocessing ----
  // deg/fill memset: exact sizes, allocations are 256B-padded apart.
  hipMemsetAsync(deg,  0, (size_t)N_NODES*4, stream);
  hipMemsetAsync(fill, 0, (size_t)N_NODES*4, stream);
  k_deg   <<<NB_E,256,0,stream>>>(dstI, deg);
  k_scan_a<<<NB_N,256,0,stream>>>(deg, incl, bsum);
  k_scan_b<<<1,  512,0,stream>>>(bsum, bexcl, NB_N);
  k_scan_c<<<NB_N,256,0,stream>>>(incl, deg, bexcl, rowptr);
  k_fill  <<<NB_E,256,0,stream>>>(srcI, dstI, rowptr, fill, csr_src, csr_eid);
  k_eamean<<<NB_W,256,0,stream>>>(rowptr, csr_eid, eatt, ea_mean);

  // ---- layer 0 ----
  k_gemm <<<NB_G,256,0,stream>>>(x, W0, nullptr, nullptr, Abf, N_NODES, 0);
  k_dots <<<NB_W,256,0,stream>>>(Abf, as0, ad0, asrc, adst);
  k_wea  <<<1,   64,0,stream>>>(We0, ae0, wea);
  k_dot16<<<NB_E,256,0,stream>>>(eatt, wea, aedge, N_EDGES);
  k_dot16<<<NB_N,256,0,stream>>>(ea_mean, wea, aloop, N_NODES);
  k_agg  <<<NB_W,256,0,stream>>>(rowptr, csr_src, csr_eid, aedge, asrc, adst, aloop, Abf, b0, B, 1);

  // ---- layer 1 ----
  k_gemm <<<NB_G,256,0,stream>>>(B, W1, nullptr, nullptr, Abf, N_NODES, 0);
  k_dots <<<NB_W,256,0,stream>>>(Abf, as1, ad1, asrc, adst);
  k_wea  <<<1,   64,0,stream>>>(We1, ae1, wea);
  k_dot16<<<NB_E,256,0,stream>>>(eatt, wea, aedge, N_EDGES);
  k_dot16<<<NB_N,256,0,stream>>>(ea_mean, wea, aloop, N_NODES);
  k_agg  <<<NB_W,256,0,stream>>>(rowptr, csr_src, csr_eid, aedge, asrc, adst, aloop, Abf, b1, B, 1);

  // ---- post MLP ----
  k_gemm <<<NB_G,256,0,stream>>>(B, l1w, l1b, A, nullptr, N_NODES, 1);
  k_lin2 <<<NB_W,256,0,stream>>>(A, l2w, l2b, out);
}

// Round 5
// 864.135 us; speedup vs baseline: 1.5721x; 1.0489x over previous
//
#include <hip/hip_runtime.h>
#include <math.h>

#define N_NODES 100000
#define N_EDGES 1600000
#define NEG 0.2f
#define MAXDEG 128
#define WPB 4   // waves per block for per-node kernels

__device__ __forceinline__ float lrelu(float x){ return x > 0.f ? x : NEG*x; }
__device__ __forceinline__ unsigned short f2bf(float f){
  unsigned int u = __float_as_uint(f);
  u += 0x7FFFu + ((u >> 16) & 1u);   // RNE
  return (unsigned short)(u >> 16);
}

// ---------------- degree count ----------------
__global__ __launch_bounds__(256) void k_deg(const int* __restrict__ dst, int* __restrict__ deg){
  int e = blockIdx.x*256 + threadIdx.x;
  if (e < N_EDGES) atomicAdd(&deg[dst[e]], 1);
}

// ---------------- exclusive scan (3 phase) ----------------
__global__ __launch_bounds__(256) void k_scan_a(const int* __restrict__ deg, int* __restrict__ incl, int* __restrict__ bsum){
  __shared__ int s[256];
  int t = threadIdx.x; int i = blockIdx.x*256 + t;
  int v = (i < N_NODES) ? deg[i] : 0;
  s[t] = v; __syncthreads();
  for (int off=1; off<256; off<<=1){
    int u = (t>=off)? s[t-off] : 0; __syncthreads();
    s[t] += u; __syncthreads();
  }
  if (i < N_NODES) incl[i] = s[t];
  if (t == 255) bsum[blockIdx.x] = s[t];
}
__global__ __launch_bounds__(512) void k_scan_b(const int* __restrict__ bsum, int* __restrict__ bexcl, int nb){
  __shared__ int s[512];
  int t = threadIdx.x;
  int v = (t<nb)? bsum[t] : 0;
  s[t] = v; __syncthreads();
  for (int off=1; off<512; off<<=1){
    int u = (t>=off)? s[t-off] : 0; __syncthreads();
    s[t] += u; __syncthreads();
  }
  if (t<nb) bexcl[t] = s[t]-v;
}
__global__ __launch_bounds__(256) void k_scan_c(const int* __restrict__ incl, const int* __restrict__ deg,
    const int* __restrict__ bexcl, int* __restrict__ rowptr){
  int i = blockIdx.x*256+threadIdx.x;
  if (i < N_NODES) rowptr[i] = incl[i] - deg[i] + bexcl[blockIdx.x];
  if (i == 0) rowptr[N_NODES] = N_EDGES;
}

// ---------------- CSR fill ----------------
// R4: interleaved (src,eid) uint2 -> ONE 8B scattered store per edge instead
// of two 4B stores into separate arrays (was 154MB WRITE_SIZE, 12x logical).
__global__ __launch_bounds__(256) void k_fill(const int* __restrict__ src, const int* __restrict__ dst,
     const int* __restrict__ rowptr, int* __restrict__ fill, uint2* __restrict__ csr_se){
  int e = blockIdx.x*256+threadIdx.x;
  if (e >= N_EDGES) return;
  int d = dst[e];
  int p = rowptr[d] + atomicAdd(&fill[d], 1);
  csr_se[p] = make_uint2((unsigned)src[e], (unsigned)e);
}

// ---------------- per-node mean of incoming edge_attr ----------------
__global__ __launch_bounds__(256) void k_eamean(const int* __restrict__ rowptr, const uint2* __restrict__ csr_se,
    const float* __restrict__ ea, float* __restrict__ ea_mean){
  int w = threadIdx.x >> 6, lane = threadIdx.x & 63;
  int n = blockIdx.x * WPB + w;          // grid is exact: n < N_NODES always
  int j = lane & 15, g = lane >> 4;
  int s0 = rowptr[n]; int deg = rowptr[n+1]-s0;
  float acc = 0.f;
  for (int i=g; i<deg; i+=4) acc += ea[(size_t)csr_se[s0+i].y*16 + j];
  acc += __shfl_xor(acc, 16);
  acc += __shfl_xor(acc, 32);
  if (lane < 16) ea_mean[n*16 + j] = acc / fmaxf((float)deg, 1.f);
}

// ---------------- fp32 GEMM: Y[M,128] = X[M,128] @ W[128,128] (+bias,relu) ----------------
// bf16 output (Ybf) fused into epilogue; fp32 (Y) optional.
__global__ __launch_bounds__(256) void k_gemm(const float* __restrict__ X, const float* __restrict__ W,
    const float* __restrict__ bias, float* __restrict__ Y, unsigned short* __restrict__ Ybf, int M, int relu){
  __shared__ float Xs[16][68];
  __shared__ float Ws[16][128];
  int t = threadIdx.x;
  int row0 = blockIdx.x * 64;
  int tc = t & 15, tr = t >> 4;
  int c0 = tc*8, r0 = tr*4;
  int lr = t >> 2, lc = (t & 3) << 2;
  int wk = t >> 4, wc = (t & 15) * 8;
  float acc[4][8];
  #pragma unroll
  for (int i=0;i<4;i++)
    #pragma unroll
    for (int j=0;j<8;j++) acc[i][j]=0.f;
  int gr = row0 + lr;
  for (int k0=0; k0<128; k0+=16){
    float4 xv = make_float4(0.f,0.f,0.f,0.f);
    if (gr < M) xv = *(const float4*)(X + (size_t)gr*128 + k0 + lc);
    float4 wv0 = *(const float4*)(W + (size_t)(k0+wk)*128 + wc);
    float4 wv1 = *(const float4*)(W + (size_t)(k0+wk)*128 + wc + 4);
    __syncthreads();
    Xs[lc+0][lr]=xv.x; Xs[lc+1][lr]=xv.y; Xs[lc+2][lr]=xv.z; Xs[lc+3][lr]=xv.w;
    *(float4*)&Ws[wk][wc]   = wv0;
    *(float4*)&Ws[wk][wc+4] = wv1;
    __syncthreads();
    #pragma unroll
    for (int kk=0;kk<16;kk++){
      float4 a  = *(const float4*)&Xs[kk][r0];
      float4 b0 = *(const float4*)&Ws[kk][c0];
      float4 b1 = *(const float4*)&Ws[kk][c0+4];
      float av[4] = {a.x,a.y,a.z,a.w};
      float bv[8] = {b0.x,b0.y,b0.z,b0.w,b1.x,b1.y,b1.z,b1.w};
      #pragma unroll
      for (int i=0;i<4;i++)
        #pragma unroll
        for (int j=0;j<8;j++) acc[i][j] += av[i]*bv[j];
    }
  }
  #pragma unroll
  for (int i=0;i<4;i++){
    int r = row0 + r0 + i;
    if (r < M){
      float v[8];
      #pragma unroll
      for (int j=0;j<8;j++){
        float u = acc[i][j] + (bias ? bias[c0+j] : 0.f);
        v[j] = relu ? fmaxf(u, 0.f) : u;
      }
      if (Y){
        *(float4*)(Y + (size_t)r*128 + c0)     = make_float4(v[0],v[1],v[2],v[3]);
        *(float4*)(Y + (size_t)r*128 + c0 + 4) = make_float4(v[4],v[5],v[6],v[7]);
      }
      if (Ybf){
        uint4 pk;
        pk.x = (unsigned)f2bf(v[0]) | ((unsigned)f2bf(v[1])<<16);
        pk.y = (unsigned)f2bf(v[2]) | ((unsigned)f2bf(v[3])<<16);
        pk.z = (unsigned)f2bf(v[4]) | ((unsigned)f2bf(v[5])<<16);
        pk.w = (unsigned)f2bf(v[6]) | ((unsigned)f2bf(v[7])<<16);
        *(uint4*)(Ybf + (size_t)r*128 + c0) = pk;
      }
    }
  }
}

// ---------------- per-node attention dot products (bf16 features) ----------------
__global__ __launch_bounds__(256) void k_dots(const unsigned short* __restrict__ xlbf, const float* __restrict__ a_s,
    const float* __restrict__ a_d, float* __restrict__ asrc, float* __restrict__ adst){
  int w = threadIdx.x >> 6, lane = threadIdx.x & 63;
  int n = blockIdx.x*WPB + w;
  unsigned int u = ((const unsigned int*)xlbf)[(size_t)n*64 + lane];
  float e0 = __uint_as_float(u << 16);
  float e1 = __uint_as_float(u & 0xFFFF0000u);
  float2 as2 = *(const float2*)(a_s + 2*lane);
  float2 ad2 = *(const float2*)(a_d + 2*lane);
  float s = e0*as2.x + e1*as2.y;
  float d = e0*ad2.x + e1*ad2.y;
  for (int off=32; off; off>>=1){ s += __shfl_xor(s,off); d += __shfl_xor(d,off); }
  if (lane==0){ asrc[n]=s; adst[n]=d; }
}

// ---------------- wea = We @ a_e (16 outputs, tiny) ----------------
__global__ __launch_bounds__(64) void k_wea(const float* __restrict__ We, const float* __restrict__ ae,
    float* __restrict__ wea){
  int t = threadIdx.x;
  if (t < 16){
    float acc = 0.f;
    for (int j=0;j<128;j++) acc += We[t*128+j]*ae[j];
    wea[t]=acc;
  }
}

// ---------------- per-row dot16 with wea ----------------
__global__ __launch_bounds__(256) void k_dot16(const float* __restrict__ ea, const float* __restrict__ wea,
    float* __restrict__ out, int count){
  int e = blockIdx.x*256+threadIdx.x;
  if (e >= count) return;
  const float4* w4 = (const float4*)wea;
  float4 w0=w4[0], w1=w4[1], w2=w4[2], w3=w4[3];
  const float4* p = (const float4*)(ea + (size_t)e*16);
  float4 a0=p[0], a1=p[1], a2=p[2], a3=p[3];
  out[e] = a0.x*w0.x+a0.y*w0.y+a0.z*w0.z+a0.w*w0.w
         + a1.x*w1.x+a1.y*w1.y+a1.z*w1.z+a1.w*w1.w
         + a2.x*w2.x+a2.y*w2.y+a2.z*w2.z+a2.w*w2.w
         + a3.x*w3.x+a3.y*w3.y+a3.z*w3.z+a3.w*w3.w;
}

// ---------------- GAT aggregation: wave per node ----------------
// R4 pass C: 4 edges per iteration. Lane group g=lane>>4 handles edge i+g;
// each lane loads uint4 = 8 bf16 cols of that edge's src row -> one
// global_load_dwordx4 covers 4 edges (16 lines) vs old 1 edge (4 lines):
// 4x fewer vmcnt waits, 4x the gather parallelism per wave. Cross-group
// combine = 2 shuffle-xors on 8 accumulators.
__global__ __launch_bounds__(256) void k_agg(const int* __restrict__ rowptr, const uint2* __restrict__ csr_se,
    const float* __restrict__ aedge, const float* __restrict__ asrc,
    const float* __restrict__ adst, const float* __restrict__ aloop, const unsigned short* __restrict__ xlbf,
    const float* __restrict__ bias, float* __restrict__ out, int relu){
  int w = threadIdx.x >> 6;
  int lane = threadIdx.x & 63;
  int n = blockIdx.x * WPB + w;          // grid exact
  __shared__ float wbuf[WPB][MAXDEG];
  __shared__ int   sbuf[WPB][MAXDEG];
  const unsigned int* xb = (const unsigned int*)xlbf;  // row = 64 uints
  int s0 = rowptr[n], s1 = rowptr[n+1];
  int deg = s1 - s0;
  float adst_n = adst[n];
  float al = lrelu(asrc[n] + adst_n + aloop[n]);   // self-loop alpha
  // pass A: alphas (lane-parallel), running max
  float m = al;
  for (int base=0; base<deg; base+=64){
    int i = base + lane;
    float a = -1e30f;
    if (i < deg){
      uint2 p2 = csr_se[s0 + i];
      int sx = (int)p2.x;
      float av = lrelu(asrc[sx] + adst_n + aedge[p2.y]);
      if (i < MAXDEG){ wbuf[w][i] = av; sbuf[w][i] = sx; }
      a = av;
    }
    for (int off=32; off; off>>=1) a = fmaxf(a, __shfl_xor(a, off));
    m = fmaxf(m, a);
  }
  // pass B: exp + sum
  float p = 0.f;
  for (int i=lane; i<deg; i+=64){
    float av;
    if (i < MAXDEG) av = wbuf[w][i];
    else { uint2 p2 = csr_se[s0+i]; av = lrelu(asrc[p2.x] + adst_n + aedge[p2.y]); }
    float ev = __expf(av - m);
    if (i < MAXDEG) wbuf[w][i] = ev;
    p += ev;
  }
  for (int off=32; off; off>>=1) p += __shfl_xor(p, off);
  float wl = __expf(al - m);
  float denom = p + wl;
  __syncthreads();   // cross-lane LDS visibility for pass C
  // pass C: 4-wide weighted gather of bf16 rows
  int g = lane >> 4, cl = lane & 15;   // group, column-slot (8 cols each)
  float acc[8];
  #pragma unroll
  for (int j=0;j<8;j++) acc[j]=0.f;
  if (g == 0){  // self-loop contribution (group 0 only)
    uint4 v = *(const uint4*)(xb + (size_t)n*64 + cl*4);
    unsigned int uu[4] = {v.x,v.y,v.z,v.w};
    #pragma unroll
    for (int q=0;q<4;q++){
      acc[2*q]   += wl * __uint_as_float(uu[q] << 16);
      acc[2*q+1] += wl * __uint_as_float(uu[q] & 0xFFFF0000u);
    }
  }
  for (int i=0; i<deg; i+=4){
    int idx = i + g;
    int sx = n; float we = 0.f;
    if (idx < deg){
      if (idx < MAXDEG){ sx = sbuf[w][idx]; we = wbuf[w][idx]; }
      else {
        uint2 p2 = csr_se[s0+idx]; sx = (int)p2.x;
        we = __expf(lrelu(asrc[sx] + adst_n + aedge[p2.y]) - m);
      }
    }
    uint4 v = *(const uint4*)(xb + (size_t)sx*64 + cl*4);
    unsigned int uu[4] = {v.x,v.y,v.z,v.w};
    #pragma unroll
    for (int q=0;q<4;q++){
      acc[2*q]   += we * __uint_as_float(uu[q] << 16);
      acc[2*q+1] += we * __uint_as_float(uu[q] & 0xFFFF0000u);
    }
  }
  #pragma unroll
  for (int j=0;j<8;j++){
    acc[j] += __shfl_xor(acc[j], 16);
    acc[j] += __shfl_xor(acc[j], 32);
  }
  if (lane < 16){
    float inv = 1.f/denom;
    float4 b0 = *(const float4*)(bias + cl*8);
    float4 b1 = *(const float4*)(bias + cl*8 + 4);
    float o[8];
    o[0]=acc[0]*inv+b0.x; o[1]=acc[1]*inv+b0.y; o[2]=acc[2]*inv+b0.z; o[3]=acc[3]*inv+b0.w;
    o[4]=acc[4]*inv+b1.x; o[5]=acc[5]*inv+b1.y; o[6]=acc[6]*inv+b1.z; o[7]=acc[7]*inv+b1.w;
    if (relu){
      #pragma unroll
      for (int j=0;j<8;j++) o[j]=fmaxf(o[j],0.f);
    }
    *(float4*)(out + (size_t)n*128 + cl*8)     = make_float4(o[0],o[1],o[2],o[3]);
    *(float4*)(out + (size_t)n*128 + cl*8 + 4) = make_float4(o[4],o[5],o[6],o[7]);
  }
}

// ---------------- lin2 (128->16) + log_softmax ----------------
__global__ __launch_bounds__(256) void k_lin2(const float* __restrict__ h, const float* __restrict__ w2,
    const float* __restrict__ b2, float* __restrict__ out){
  __shared__ float w2s[2048];
  __shared__ float b2s[16];
  __shared__ float hs[64*132];
  int t = threadIdx.x;
  int n0 = blockIdx.x * 64;
  #pragma unroll
  for (int i=0;i<2;i++) ((float4*)w2s)[t + i*256] = ((const float4*)w2)[t + i*256];
  if (t < 16) b2s[t] = b2[t];
  int nmax = N_NODES - n0; if (nmax > 64) nmax = 64;
  for (int i=t; i < nmax*32; i += 256){
    int nl = i >> 5, c4 = i & 31;
    float4 v = *(const float4*)(h + (size_t)(n0+nl)*128 + c4*4);
    *(float4*)&hs[nl*132 + c4*4] = v;
  }
  __syncthreads();
  int nl = t >> 2, cq = (t & 3) * 4;
  int n = n0 + nl;
  if (n < N_NODES){
    float acc0=b2s[cq], acc1=b2s[cq+1], acc2=b2s[cq+2], acc3=b2s[cq+3];
    const float* hp = &hs[nl*132];
    #pragma unroll 8
    for (int k=0;k<128;k++){
      float hv = hp[k];
      float4 w4 = *(const float4*)&w2s[k*16 + cq];
      acc0 += hv*w4.x; acc1 += hv*w4.y; acc2 += hv*w4.z; acc3 += hv*w4.w;
    }
    float m = fmaxf(fmaxf(acc0,acc1), fmaxf(acc2,acc3));
    m = fmaxf(m, __shfl_xor(m, 1));
    m = fmaxf(m, __shfl_xor(m, 2));
    float s = __expf(acc0-m)+__expf(acc1-m)+__expf(acc2-m)+__expf(acc3-m);
    s += __shfl_xor(s, 1);
    s += __shfl_xor(s, 2);
    float lse = m + __logf(s);
    float4 o = make_float4(acc0-lse, acc1-lse, acc2-lse, acc3-lse);
    *(float4*)(out + (size_t)n*16 + cq) = o;
  }
}

extern "C" void kernel_launch(void* const* d_in, const int* in_sizes, int n_in,
                              void* d_out, int out_size, void* d_ws, size_t ws_size,
                              hipStream_t stream){
  const float* x    = (const float*)d_in[0];
  const float* eatt = (const float*)d_in[1];
  const float* W0   = (const float*)d_in[2];
  const float* as0  = (const float*)d_in[3];
  const float* ad0  = (const float*)d_in[4];
  const float* We0  = (const float*)d_in[5];
  const float* ae0  = (const float*)d_in[6];
  const float* b0   = (const float*)d_in[7];
  const float* W1   = (const float*)d_in[8];
  const float* as1  = (const float*)d_in[9];
  const float* ad1  = (const float*)d_in[10];
  const float* We1  = (const float*)d_in[11];
  const float* ae1  = (const float*)d_in[12];
  const float* b1   = (const float*)d_in[13];
  const float* l1w  = (const float*)d_in[14];
  const float* l1b  = (const float*)d_in[15];
  const float* l2w  = (const float*)d_in[16];
  const float* l2b  = (const float*)d_in[17];
  const int*   ei   = (const int*)d_in[18];
  const int* srcI = ei;
  const int* dstI = ei + N_EDGES;
  float* out = (float*)d_out;

  char* p = (char*)d_ws;
  auto alloc = [&](size_t bytes)->char*{ char* r = p; p += (bytes + 255) & ~255ull; return r; };
  float* A       = (float*)alloc((size_t)N_NODES*128*4);   // fp32 features (lin1 out)
  unsigned short* Abf = (unsigned short*)alloc((size_t)N_NODES*128*2); // bf16 features (GAT layers)
  float* B       = (float*)alloc((size_t)N_NODES*128*4);   // aggregation output
  float* ea_mean = (float*)alloc((size_t)N_NODES*16*4);
  float* aedge   = (float*)alloc((size_t)N_EDGES*4);
  float* asrc    = (float*)alloc((size_t)N_NODES*4);
  float* adst    = (float*)alloc((size_t)N_NODES*4);
  float* aloop   = (float*)alloc((size_t)N_NODES*4);
  float* wea     = (float*)alloc(64);
  int* deg     = (int*)alloc((size_t)N_NODES*4);
  int* fill    = (int*)alloc((size_t)N_NODES*4);
  int* rowptr  = (int*)alloc((size_t)(N_NODES+1)*4);
  uint2* csr_se = (uint2*)alloc((size_t)N_EDGES*8);
  int* incl    = (int*)alloc((size_t)N_NODES*4);
  int* bsum    = (int*)alloc(512*4);
  int* bexcl   = (int*)alloc(512*4);

  const int NB_E = (N_EDGES+255)/256;   // 6250
  const int NB_N = (N_NODES+255)/256;   // 391
  const int NB_W = N_NODES/WPB;         // 25000 (exact)
  const int NB_G = (N_NODES+63)/64;     // 1563

  // ---- shared preprocessing ----
  hipMemsetAsync(deg,  0, (size_t)N_NODES*4, stream);
  hipMemsetAsync(fill, 0, (size_t)N_NODES*4, stream);
  k_deg   <<<NB_E,256,0,stream>>>(dstI, deg);
  k_scan_a<<<NB_N,256,0,stream>>>(deg, incl, bsum);
  k_scan_b<<<1,  512,0,stream>>>(bsum, bexcl, NB_N);
  k_scan_c<<<NB_N,256,0,stream>>>(incl, deg, bexcl, rowptr);
  k_fill  <<<NB_E,256,0,stream>>>(srcI, dstI, rowptr, fill, csr_se);
  k_eamean<<<NB_W,256,0,stream>>>(rowptr, csr_se, eatt, ea_mean);

  // ---- layer 0 ----
  k_gemm <<<NB_G,256,0,stream>>>(x, W0, nullptr, nullptr, Abf, N_NODES, 0);
  k_dots <<<NB_W,256,0,stream>>>(Abf, as0, ad0, asrc, adst);
  k_wea  <<<1,   64,0,stream>>>(We0, ae0, wea);
  k_dot16<<<NB_E,256,0,stream>>>(eatt, wea, aedge, N_EDGES);
  k_dot16<<<NB_N,256,0,stream>>>(ea_mean, wea, aloop, N_NODES);
  k_agg  <<<NB_W,256,0,stream>>>(rowptr, csr_se, aedge, asrc, adst, aloop, Abf, b0, B, 1);

  // ---- layer 1 ----
  k_gemm <<<NB_G,256,0,stream>>>(B, W1, nullptr, nullptr, Abf, N_NODES, 0);
  k_dots <<<NB_W,256,0,stream>>>(Abf, as1, ad1, asrc, adst);
  k_wea  <<<1,   64,0,stream>>>(We1, ae1, wea);
  k_dot16<<<NB_E,256,0,stream>>>(eatt, wea, aedge, N_EDGES);
  k_dot16<<<NB_N,256,0,stream>>>(ea_mean, wea, aloop, N_NODES);
  k_agg  <<<NB_W,256,0,stream>>>(rowptr, csr_se, aedge, asrc, adst, aloop, Abf, b1, B, 1);

  // ---- post MLP ----
  k_gemm <<<NB_G,256,0,stream>>>(B, l1w, l1b, A, nullptr, N_NODES, 1);
  k_lin2 <<<NB_W,256,0,stream>>>(A, l2w, l2b, out);
}

// Round 6
// 784.992 us; speedup vs baseline: 1.7306x; 1.1008x over previous
//
#include <hip/hip_runtime.h>
#include <math.h>

#define N_NODES 100000
#define N_EDGES 1600000
#define NEG 0.2f
#define MAXDEG 128
#define WPB 4   // waves per block for per-node kernels

__device__ __forceinline__ float lrelu(float x){ return x > 0.f ? x : NEG*x; }
__device__ __forceinline__ unsigned short f2bf(float f){
  unsigned int u = __float_as_uint(f);
  u += 0x7FFFu + ((u >> 16) & 1u);   // RNE
  return (unsigned short)(u >> 16);
}

// ---------------- degree count ----------------
__global__ __launch_bounds__(256) void k_deg(const int* __restrict__ dst, int* __restrict__ deg){
  int e = blockIdx.x*256 + threadIdx.x;
  if (e < N_EDGES) atomicAdd(&deg[dst[e]], 1);
}

// ---------------- exclusive scan (3 phase) ----------------
__global__ __launch_bounds__(256) void k_scan_a(const int* __restrict__ deg, int* __restrict__ incl, int* __restrict__ bsum){
  __shared__ int s[256];
  int t = threadIdx.x; int i = blockIdx.x*256 + t;
  int v = (i < N_NODES) ? deg[i] : 0;
  s[t] = v; __syncthreads();
  for (int off=1; off<256; off<<=1){
    int u = (t>=off)? s[t-off] : 0; __syncthreads();
    s[t] += u; __syncthreads();
  }
  if (i < N_NODES) incl[i] = s[t];
  if (t == 255) bsum[blockIdx.x] = s[t];
}
__global__ __launch_bounds__(512) void k_scan_b(const int* __restrict__ bsum, int* __restrict__ bexcl, int nb){
  __shared__ int s[512];
  int t = threadIdx.x;
  int v = (t<nb)? bsum[t] : 0;
  s[t] = v; __syncthreads();
  for (int off=1; off<512; off<<=1){
    int u = (t>=off)? s[t-off] : 0; __syncthreads();
    s[t] += u; __syncthreads();
  }
  if (t<nb) bexcl[t] = s[t]-v;
}
__global__ __launch_bounds__(256) void k_scan_c(const int* __restrict__ incl, const int* __restrict__ deg,
    const int* __restrict__ bexcl, int* __restrict__ rowptr){
  int i = blockIdx.x*256+threadIdx.x;
  if (i < N_NODES) rowptr[i] = incl[i] - deg[i] + bexcl[blockIdx.x];
  if (i == 0) rowptr[N_NODES] = N_EDGES;
}

// ---------------- CSR fill (interleaved src,eid: one 8B store/edge) ----------------
__global__ __launch_bounds__(256) void k_fill(const int* __restrict__ src, const int* __restrict__ dst,
     const int* __restrict__ rowptr, int* __restrict__ fill, uint2* __restrict__ csr_se){
  int e = blockIdx.x*256+threadIdx.x;
  if (e >= N_EDGES) return;
  int d = dst[e];
  int p = rowptr[d] + atomicAdd(&fill[d], 1);
  csr_se[p] = make_uint2((unsigned)src[e], (unsigned)e);
}

// ---------------- fp32 GEMM: Y[M,128] = X[M,128] @ W[128,128] (+bias,relu) ----------------
__global__ __launch_bounds__(256) void k_gemm(const float* __restrict__ X, const float* __restrict__ W,
    const float* __restrict__ bias, float* __restrict__ Y, unsigned short* __restrict__ Ybf, int M, int relu){
  __shared__ float Xs[16][68];
  __shared__ float Ws[16][128];
  int t = threadIdx.x;
  int row0 = blockIdx.x * 64;
  int tc = t & 15, tr = t >> 4;
  int c0 = tc*8, r0 = tr*4;
  int lr = t >> 2, lc = (t & 3) << 2;
  int wk = t >> 4, wc = (t & 15) * 8;
  float acc[4][8];
  #pragma unroll
  for (int i=0;i<4;i++)
    #pragma unroll
    for (int j=0;j<8;j++) acc[i][j]=0.f;
  int gr = row0 + lr;
  for (int k0=0; k0<128; k0+=16){
    float4 xv = make_float4(0.f,0.f,0.f,0.f);
    if (gr < M) xv = *(const float4*)(X + (size_t)gr*128 + k0 + lc);
    float4 wv0 = *(const float4*)(W + (size_t)(k0+wk)*128 + wc);
    float4 wv1 = *(const float4*)(W + (size_t)(k0+wk)*128 + wc + 4);
    __syncthreads();
    Xs[lc+0][lr]=xv.x; Xs[lc+1][lr]=xv.y; Xs[lc+2][lr]=xv.z; Xs[lc+3][lr]=xv.w;
    *(float4*)&Ws[wk][wc]   = wv0;
    *(float4*)&Ws[wk][wc+4] = wv1;
    __syncthreads();
    #pragma unroll
    for (int kk=0;kk<16;kk++){
      float4 a  = *(const float4*)&Xs[kk][r0];
      float4 b0 = *(const float4*)&Ws[kk][c0];
      float4 b1 = *(const float4*)&Ws[kk][c0+4];
      float av[4] = {a.x,a.y,a.z,a.w};
      float bv[8] = {b0.x,b0.y,b0.z,b0.w,b1.x,b1.y,b1.z,b1.w};
      #pragma unroll
      for (int i=0;i<4;i++)
        #pragma unroll
        for (int j=0;j<8;j++) acc[i][j] += av[i]*bv[j];
    }
  }
  #pragma unroll
  for (int i=0;i<4;i++){
    int r = row0 + r0 + i;
    if (r < M){
      float v[8];
      #pragma unroll
      for (int j=0;j<8;j++){
        float u = acc[i][j] + (bias ? bias[c0+j] : 0.f);
        v[j] = relu ? fmaxf(u, 0.f) : u;
      }
      if (Y){
        *(float4*)(Y + (size_t)r*128 + c0)     = make_float4(v[0],v[1],v[2],v[3]);
        *(float4*)(Y + (size_t)r*128 + c0 + 4) = make_float4(v[4],v[5],v[6],v[7]);
      }
      if (Ybf){
        uint4 pk;
        pk.x = (unsigned)f2bf(v[0]) | ((unsigned)f2bf(v[1])<<16);
        pk.y = (unsigned)f2bf(v[2]) | ((unsigned)f2bf(v[3])<<16);
        pk.z = (unsigned)f2bf(v[4]) | ((unsigned)f2bf(v[5])<<16);
        pk.w = (unsigned)f2bf(v[6]) | ((unsigned)f2bf(v[7])<<16);
        *(uint4*)(Ybf + (size_t)r*128 + c0) = pk;
      }
    }
  }
}

// ---------------- per-node attention dot products (bf16 features) ----------------
__global__ __launch_bounds__(256) void k_dots(const unsigned short* __restrict__ xlbf, const float* __restrict__ a_s,
    const float* __restrict__ a_d, float* __restrict__ asrc, float* __restrict__ adst){
  int w = threadIdx.x >> 6, lane = threadIdx.x & 63;
  int n = blockIdx.x*WPB + w;
  unsigned int u = ((const unsigned int*)xlbf)[(size_t)n*64 + lane];
  float e0 = __uint_as_float(u << 16);
  float e1 = __uint_as_float(u & 0xFFFF0000u);
  float2 as2 = *(const float2*)(a_s + 2*lane);
  float2 ad2 = *(const float2*)(a_d + 2*lane);
  float s = e0*as2.x + e1*as2.y;
  float d = e0*ad2.x + e1*ad2.y;
  for (int off=32; off; off>>=1){ s += __shfl_xor(s,off); d += __shfl_xor(d,off); }
  if (lane==0){ asrc[n]=s; adst[n]=d; }
}

// ---------------- wea_l = We_l @ a_e_l for BOTH layers (32 outputs, tiny) ----------------
__global__ __launch_bounds__(64) void k_wea2(const float* __restrict__ We0, const float* __restrict__ ae0,
    const float* __restrict__ We1, const float* __restrict__ ae1, float* __restrict__ wea01){
  int t = threadIdx.x;
  if (t < 16){
    float acc = 0.f;
    for (int j=0;j<128;j++) acc += We0[t*128+j]*ae0[j];
    wea01[t]=acc;
  } else if (t < 32){
    int r = t - 16;
    float acc = 0.f;
    for (int j=0;j<128;j++) acc += We1[r*128+j]*ae1[j];
    wea01[t]=acc;
  }
}

// ---------------- one pass over eatt: aedge for BOTH layers ----------------
// (R5: was two full 102MB reads of eatt; now one)
__global__ __launch_bounds__(256) void k_dot16x2(const float* __restrict__ ea, const float* __restrict__ wea01,
    float* __restrict__ out0, float* __restrict__ out1){
  int e = blockIdx.x*256+threadIdx.x;
  if (e >= N_EDGES) return;
  const float4* w4 = (const float4*)wea01;
  float4 u0=w4[0], u1=w4[1], u2=w4[2], u3=w4[3];   // wea0
  float4 v0=w4[4], v1=w4[5], v2=w4[6], v3=w4[7];   // wea1
  const float4* p = (const float4*)(ea + (size_t)e*16);
  float4 a0=p[0], a1=p[1], a2=p[2], a3=p[3];
  out0[e] = a0.x*u0.x+a0.y*u0.y+a0.z*u0.z+a0.w*u0.w
          + a1.x*u1.x+a1.y*u1.y+a1.z*u1.z+a1.w*u1.w
          + a2.x*u2.x+a2.y*u2.y+a2.z*u2.z+a2.w*u2.w
          + a3.x*u3.x+a3.y*u3.y+a3.z*u3.z+a3.w*u3.w;
  out1[e] = a0.x*v0.x+a0.y*v0.y+a0.z*v0.z+a0.w*v0.w
          + a1.x*v1.x+a1.y*v1.y+a1.z*v1.z+a1.w*v1.w
          + a2.x*v2.x+a2.y*v2.y+a2.z*v2.z+a2.w*v2.w
          + a3.x*v3.x+a3.y*v3.y+a3.z*v3.z+a3.w*v3.w;
}

// ---------------- GAT aggregation: wave per node ----------------
// R5: aloop fused into pass A. Self-loop alpha uses mean(incoming edge_attr)@wea,
// and mean commutes with the linear map: aloop[n] = mean(aedge[e] : e->n).
// Pass A already reads aedge per edge -> accumulate sum alongside max.
// Eliminates the entire ea_mean pipeline (102MB random gather kernel + 2 dot16s).
__global__ __launch_bounds__(256) void k_agg(const int* __restrict__ rowptr, const uint2* __restrict__ csr_se,
    const float* __restrict__ aedge, const float* __restrict__ asrc,
    const float* __restrict__ adst, const unsigned short* __restrict__ xlbf,
    const float* __restrict__ bias, float* __restrict__ out, int relu){
  int w = threadIdx.x >> 6;
  int lane = threadIdx.x & 63;
  int n = blockIdx.x * WPB + w;          // grid exact
  __shared__ float wbuf[WPB][MAXDEG];
  __shared__ int   sbuf[WPB][MAXDEG];
  const unsigned int* xb = (const unsigned int*)xlbf;  // row = 64 uints
  int s0 = rowptr[n], s1 = rowptr[n+1];
  int deg = s1 - s0;
  float adst_n = adst[n];
  // pass A: alphas (lane-parallel), running max + aedge sum (for self-loop)
  float m_edge = -1e30f;
  float sae = 0.f;
  for (int base=0; base<deg; base+=64){
    int i = base + lane;
    float a = -1e30f;
    if (i < deg){
      uint2 p2 = csr_se[s0 + i];
      int sx = (int)p2.x;
      float ae = aedge[p2.y];
      float av = lrelu(asrc[sx] + adst_n + ae);
      if (i < MAXDEG){ wbuf[w][i] = av; sbuf[w][i] = sx; }
      a = av;
      sae += ae;
    }
    for (int off=32; off; off>>=1) a = fmaxf(a, __shfl_xor(a, off));
    m_edge = fmaxf(m_edge, a);
  }
  for (int off=32; off; off>>=1) sae += __shfl_xor(sae, off);
  float aloop_n = sae / fmaxf((float)deg, 1.f);
  float al = lrelu(asrc[n] + adst_n + aloop_n);   // self-loop alpha
  float m = fmaxf(m_edge, al);
  // pass B: exp + sum
  float p = 0.f;
  for (int i=lane; i<deg; i+=64){
    float av;
    if (i < MAXDEG) av = wbuf[w][i];
    else { uint2 p2 = csr_se[s0+i]; av = lrelu(asrc[p2.x] + adst_n + aedge[p2.y]); }
    float ev = __expf(av - m);
    if (i < MAXDEG) wbuf[w][i] = ev;
    p += ev;
  }
  for (int off=32; off; off>>=1) p += __shfl_xor(p, off);
  float wl = __expf(al - m);
  float denom = p + wl;
  __syncthreads();   // cross-lane LDS visibility for pass C
  // pass C: 4-wide weighted gather of bf16 rows
  int g = lane >> 4, cl = lane & 15;   // group, column-slot (8 cols each)
  float acc[8];
  #pragma unroll
  for (int j=0;j<8;j++) acc[j]=0.f;
  if (g == 0){  // self-loop contribution (group 0 only)
    uint4 v = *(const uint4*)(xb + (size_t)n*64 + cl*4);
    unsigned int uu[4] = {v.x,v.y,v.z,v.w};
    #pragma unroll
    for (int q=0;q<4;q++){
      acc[2*q]   += wl * __uint_as_float(uu[q] << 16);
      acc[2*q+1] += wl * __uint_as_float(uu[q] & 0xFFFF0000u);
    }
  }
  for (int i=0; i<deg; i+=4){
    int idx = i + g;
    int sx = n; float we = 0.f;
    if (idx < deg){
      if (idx < MAXDEG){ sx = sbuf[w][idx]; we = wbuf[w][idx]; }
      else {
        uint2 p2 = csr_se[s0+idx]; sx = (int)p2.x;
        we = __expf(lrelu(asrc[sx] + adst_n + aedge[p2.y]) - m);
      }
    }
    uint4 v = *(const uint4*)(xb + (size_t)sx*64 + cl*4);
    unsigned int uu[4] = {v.x,v.y,v.z,v.w};
    #pragma unroll
    for (int q=0;q<4;q++){
      acc[2*q]   += we * __uint_as_float(uu[q] << 16);
      acc[2*q+1] += we * __uint_as_float(uu[q] & 0xFFFF0000u);
    }
  }
  #pragma unroll
  for (int j=0;j<8;j++){
    acc[j] += __shfl_xor(acc[j], 16);
    acc[j] += __shfl_xor(acc[j], 32);
  }
  if (lane < 16){
    float inv = 1.f/denom;
    float4 b0 = *(const float4*)(bias + cl*8);
    float4 b1 = *(const float4*)(bias + cl*8 + 4);
    float o[8];
    o[0]=acc[0]*inv+b0.x; o[1]=acc[1]*inv+b0.y; o[2]=acc[2]*inv+b0.z; o[3]=acc[3]*inv+b0.w;
    o[4]=acc[4]*inv+b1.x; o[5]=acc[5]*inv+b1.y; o[6]=acc[6]*inv+b1.z; o[7]=acc[7]*inv+b1.w;
    if (relu){
      #pragma unroll
      for (int j=0;j<8;j++) o[j]=fmaxf(o[j],0.f);
    }
    *(float4*)(out + (size_t)n*128 + cl*8)     = make_float4(o[0],o[1],o[2],o[3]);
    *(float4*)(out + (size_t)n*128 + cl*8 + 4) = make_float4(o[4],o[5],o[6],o[7]);
  }
}

// ---------------- lin2 (128->16) + log_softmax ----------------
__global__ __launch_bounds__(256) void k_lin2(const float* __restrict__ h, const float* __restrict__ w2,
    const float* __restrict__ b2, float* __restrict__ out){
  __shared__ float w2s[2048];
  __shared__ float b2s[16];
  __shared__ float hs[64*132];
  int t = threadIdx.x;
  int n0 = blockIdx.x * 64;
  #pragma unroll
  for (int i=0;i<2;i++) ((float4*)w2s)[t + i*256] = ((const float4*)w2)[t + i*256];
  if (t < 16) b2s[t] = b2[t];
  int nmax = N_NODES - n0; if (nmax > 64) nmax = 64;
  for (int i=t; i < nmax*32; i += 256){
    int nl = i >> 5, c4 = i & 31;
    float4 v = *(const float4*)(h + (size_t)(n0+nl)*128 + c4*4);
    *(float4*)&hs[nl*132 + c4*4] = v;
  }
  __syncthreads();
  int nl = t >> 2, cq = (t & 3) * 4;
  int n = n0 + nl;
  if (n < N_NODES){
    float acc0=b2s[cq], acc1=b2s[cq+1], acc2=b2s[cq+2], acc3=b2s[cq+3];
    const float* hp = &hs[nl*132];
    #pragma unroll 8
    for (int k=0;k<128;k++){
      float hv = hp[k];
      float4 w4 = *(const float4*)&w2s[k*16 + cq];
      acc0 += hv*w4.x; acc1 += hv*w4.y; acc2 += hv*w4.z; acc3 += hv*w4.w;
    }
    float m = fmaxf(fmaxf(acc0,acc1), fmaxf(acc2,acc3));
    m = fmaxf(m, __shfl_xor(m, 1));
    m = fmaxf(m, __shfl_xor(m, 2));
    float s = __expf(acc0-m)+__expf(acc1-m)+__expf(acc2-m)+__expf(acc3-m);
    s += __shfl_xor(s, 1);
    s += __shfl_xor(s, 2);
    float lse = m + __logf(s);
    float4 o = make_float4(acc0-lse, acc1-lse, acc2-lse, acc3-lse);
    *(float4*)(out + (size_t)n*16 + cq) = o;
  }
}

extern "C" void kernel_launch(void* const* d_in, const int* in_sizes, int n_in,
                              void* d_out, int out_size, void* d_ws, size_t ws_size,
                              hipStream_t stream){
  const float* x    = (const float*)d_in[0];
  const float* eatt = (const float*)d_in[1];
  const float* W0   = (const float*)d_in[2];
  const float* as0  = (const float*)d_in[3];
  const float* ad0  = (const float*)d_in[4];
  const float* We0  = (const float*)d_in[5];
  const float* ae0  = (const float*)d_in[6];
  const float* b0   = (const float*)d_in[7];
  const float* W1   = (const float*)d_in[8];
  const float* as1  = (const float*)d_in[9];
  const float* ad1  = (const float*)d_in[10];
  const float* We1  = (const float*)d_in[11];
  const float* ae1  = (const float*)d_in[12];
  const float* b1   = (const float*)d_in[13];
  const float* l1w  = (const float*)d_in[14];
  const float* l1b  = (const float*)d_in[15];
  const float* l2w  = (const float*)d_in[16];
  const float* l2b  = (const float*)d_in[17];
  const int*   ei   = (const int*)d_in[18];
  const int* srcI = ei;
  const int* dstI = ei + N_EDGES;
  float* out = (float*)d_out;

  char* p = (char*)d_ws;
  auto alloc = [&](size_t bytes)->char*{ char* r = p; p += (bytes + 255) & ~255ull; return r; };
  float* A       = (float*)alloc((size_t)N_NODES*128*4);   // fp32 features (lin1 out)
  unsigned short* Abf = (unsigned short*)alloc((size_t)N_NODES*128*2); // bf16 features (GAT layers)
  float* B       = (float*)alloc((size_t)N_NODES*128*4);   // aggregation output
  float* aedge0  = (float*)alloc((size_t)N_EDGES*4);
  float* aedge1  = (float*)alloc((size_t)N_EDGES*4);
  float* asrc    = (float*)alloc((size_t)N_NODES*4);
  float* adst    = (float*)alloc((size_t)N_NODES*4);
  float* wea01   = (float*)alloc(128);
  int* deg     = (int*)alloc((size_t)N_NODES*4);
  int* fill    = (int*)alloc((size_t)N_NODES*4);
  int* rowptr  = (int*)alloc((size_t)(N_NODES+1)*4);
  uint2* csr_se = (uint2*)alloc((size_t)N_EDGES*8);
  int* incl    = (int*)alloc((size_t)N_NODES*4);
  int* bsum    = (int*)alloc(512*4);
  int* bexcl   = (int*)alloc(512*4);

  const int NB_E = (N_EDGES+255)/256;   // 6250
  const int NB_N = (N_NODES+255)/256;   // 391
  const int NB_W = N_NODES/WPB;         // 25000 (exact)
  const int NB_G = (N_NODES+63)/64;     // 1563

  // ---- shared preprocessing ----
  hipMemsetAsync(deg,  0, (size_t)N_NODES*4, stream);
  hipMemsetAsync(fill, 0, (size_t)N_NODES*4, stream);
  k_deg    <<<NB_E,256,0,stream>>>(dstI, deg);
  k_scan_a <<<NB_N,256,0,stream>>>(deg, incl, bsum);
  k_scan_b <<<1,  512,0,stream>>>(bsum, bexcl, NB_N);
  k_scan_c <<<NB_N,256,0,stream>>>(incl, deg, bexcl, rowptr);
  k_fill   <<<NB_E,256,0,stream>>>(srcI, dstI, rowptr, fill, csr_se);
  k_wea2   <<<1,   64,0,stream>>>(We0, ae0, We1, ae1, wea01);
  k_dot16x2<<<NB_E,256,0,stream>>>(eatt, wea01, aedge0, aedge1);

  // ---- layer 0 ----
  k_gemm <<<NB_G,256,0,stream>>>(x, W0, nullptr, nullptr, Abf, N_NODES, 0);
  k_dots <<<NB_W,256,0,stream>>>(Abf, as0, ad0, asrc, adst);
  k_agg  <<<NB_W,256,0,stream>>>(rowptr, csr_se, aedge0, asrc, adst, Abf, b0, B, 1);

  // ---- layer 1 ----
  k_gemm <<<NB_G,256,0,stream>>>(B, W1, nullptr, nullptr, Abf, N_NODES, 0);
  k_dots <<<NB_W,256,0,stream>>>(Abf, as1, ad1, asrc, adst);
  k_agg  <<<NB_W,256,0,stream>>>(rowptr, csr_se, aedge1, asrc, adst, Abf, b1, B, 1);

  // ---- post MLP ----
  k_gemm <<<NB_G,256,0,stream>>>(B, l1w, l1b, A, nullptr, N_NODES, 1);
  k_lin2 <<<NB_W,256,0,stream>>>(A, l2w, l2b, out);
}

// Round 7
// 680.793 us; speedup vs baseline: 1.9955x; 1.1531x over previous
//
#include <hip/hip_runtime.h>
#include <math.h>

#define N_NODES 100000
#define N_EDGES 1600000
#define NEG 0.2f
#define MAXDEG 128
#define WPB 4   // waves per block for per-node kernels

__device__ __forceinline__ float lrelu(float x){ return x > 0.f ? x : NEG*x; }
__device__ __forceinline__ unsigned short f2bf(float f){
  unsigned int u = __float_as_uint(f);
  u += 0x7FFFu + ((u >> 16) & 1u);   // RNE
  return (unsigned short)(u >> 16);
}

// ---------------- degree count ----------------
__global__ __launch_bounds__(256) void k_deg(const int* __restrict__ dst, int* __restrict__ deg){
  int e = blockIdx.x*256 + threadIdx.x;
  if (e < N_EDGES) atomicAdd(&deg[dst[e]], 1);
}

// ---------------- exclusive scan (3 phase) ----------------
__global__ __launch_bounds__(256) void k_scan_a(const int* __restrict__ deg, int* __restrict__ incl, int* __restrict__ bsum){
  __shared__ int s[256];
  int t = threadIdx.x; int i = blockIdx.x*256 + t;
  int v = (i < N_NODES) ? deg[i] : 0;
  s[t] = v; __syncthreads();
  for (int off=1; off<256; off<<=1){
    int u = (t>=off)? s[t-off] : 0; __syncthreads();
    s[t] += u; __syncthreads();
  }
  if (i < N_NODES) incl[i] = s[t];
  if (t == 255) bsum[blockIdx.x] = s[t];
}
// R6: scan_b also computes wea01 (We_l @ a_e_l, 32 dots of length 128) in
// spare threads — eliminates the k_wea2 dispatch.
__global__ __launch_bounds__(512) void k_scan_b(const int* __restrict__ bsum, int* __restrict__ bexcl, int nb,
    const float* __restrict__ We0, const float* __restrict__ ae0,
    const float* __restrict__ We1, const float* __restrict__ ae1, float* __restrict__ wea01){
  __shared__ int s[512];
  int t = threadIdx.x;
  int v = (t<nb)? bsum[t] : 0;
  s[t] = v; __syncthreads();
  for (int off=1; off<512; off<<=1){
    int u = (t>=off)? s[t-off] : 0; __syncthreads();
    s[t] += u; __syncthreads();
  }
  if (t<nb) bexcl[t] = s[t]-v;
  if (t < 16){
    float acc = 0.f;
    for (int j=0;j<128;j++) acc += We0[t*128+j]*ae0[j];
    wea01[t]=acc;
  } else if (t < 32){
    int r = t - 16;
    float acc = 0.f;
    for (int j=0;j<128;j++) acc += We1[r*128+j]*ae1[j];
    wea01[t]=acc;
  }
}
__global__ __launch_bounds__(256) void k_scan_c(const int* __restrict__ incl, const int* __restrict__ deg,
    const int* __restrict__ bexcl, int* __restrict__ rowptr){
  int i = blockIdx.x*256+threadIdx.x;
  if (i < N_NODES) rowptr[i] = incl[i] - deg[i] + bexcl[blockIdx.x];
  if (i == 0) rowptr[N_NODES] = N_EDGES;
}

// ---------------- fused CSR fill + edge attention dots ----------------
// R6: csr record = uint4(src, ae0_bits, ae1_bits, 0). One 16B scattered
// store per edge. Absorbs k_dot16x2 (eatt read is coalesced here) and turns
// k_agg's random aedge[eid] gather into part of the coalesced CSR read.
__global__ __launch_bounds__(256) void k_fillf(const int* __restrict__ src, const int* __restrict__ dst,
     const int* __restrict__ rowptr, int* __restrict__ fill,
     const float* __restrict__ eatt, const float* __restrict__ wea01, uint4* __restrict__ csr){
  int e = blockIdx.x*256+threadIdx.x;
  if (e >= N_EDGES) return;
  const float4* w4 = (const float4*)wea01;
  float4 u0=w4[0], u1=w4[1], u2=w4[2], u3=w4[3];   // wea0
  float4 v0=w4[4], v1=w4[5], v2=w4[6], v3=w4[7];   // wea1
  const float4* p = (const float4*)(eatt + (size_t)e*16);
  float4 a0=p[0], a1=p[1], a2=p[2], a3=p[3];
  float ae0 = a0.x*u0.x+a0.y*u0.y+a0.z*u0.z+a0.w*u0.w
            + a1.x*u1.x+a1.y*u1.y+a1.z*u1.z+a1.w*u1.w
            + a2.x*u2.x+a2.y*u2.y+a2.z*u2.z+a2.w*u2.w
            + a3.x*u3.x+a3.y*u3.y+a3.z*u3.z+a3.w*u3.w;
  float ae1 = a0.x*v0.x+a0.y*v0.y+a0.z*v0.z+a0.w*v0.w
            + a1.x*v1.x+a1.y*v1.y+a1.z*v1.z+a1.w*v1.w
            + a2.x*v2.x+a2.y*v2.y+a2.z*v2.z+a2.w*v2.w
            + a3.x*v3.x+a3.y*v3.y+a3.z*v3.z+a3.w*v3.w;
  int d = dst[e];
  int pos = rowptr[d] + atomicAdd(&fill[d], 1);
  csr[pos] = make_uint4((unsigned)src[e], __float_as_uint(ae0), __float_as_uint(ae1), 0u);
}

// ---------------- fp32 GEMM + optional fused attention dots ----------------
// R6: when a_s != nullptr, the epilogue computes asrc/adst per row via a
// 16-lane shuffle reduce (block holds full 128-wide rows) — kills k_dots.
__global__ __launch_bounds__(256) void k_gemm(const float* __restrict__ X, const float* __restrict__ W,
    const float* __restrict__ bias, float* __restrict__ Y, unsigned short* __restrict__ Ybf,
    const float* __restrict__ a_s, const float* __restrict__ a_d,
    float* __restrict__ asrc, float* __restrict__ adst, int M, int relu){
  __shared__ float Xs[16][68];
  __shared__ float Ws[16][128];
  __shared__ float as_s[128], ad_s[128];
  int t = threadIdx.x;
  if (a_s && t < 128){ as_s[t] = a_s[t]; ad_s[t] = a_d[t]; }
  int row0 = blockIdx.x * 64;
  int tc = t & 15, tr = t >> 4;
  int c0 = tc*8, r0 = tr*4;
  int lr = t >> 2, lc = (t & 3) << 2;
  int wk = t >> 4, wc = (t & 15) * 8;
  float acc[4][8];
  #pragma unroll
  for (int i=0;i<4;i++)
    #pragma unroll
    for (int j=0;j<8;j++) acc[i][j]=0.f;
  int gr = row0 + lr;
  for (int k0=0; k0<128; k0+=16){
    float4 xv = make_float4(0.f,0.f,0.f,0.f);
    if (gr < M) xv = *(const float4*)(X + (size_t)gr*128 + k0 + lc);
    float4 wv0 = *(const float4*)(W + (size_t)(k0+wk)*128 + wc);
    float4 wv1 = *(const float4*)(W + (size_t)(k0+wk)*128 + wc + 4);
    __syncthreads();
    Xs[lc+0][lr]=xv.x; Xs[lc+1][lr]=xv.y; Xs[lc+2][lr]=xv.z; Xs[lc+3][lr]=xv.w;
    *(float4*)&Ws[wk][wc]   = wv0;
    *(float4*)&Ws[wk][wc+4] = wv1;
    __syncthreads();
    #pragma unroll
    for (int kk=0;kk<16;kk++){
      float4 a  = *(const float4*)&Xs[kk][r0];
      float4 b0 = *(const float4*)&Ws[kk][c0];
      float4 b1 = *(const float4*)&Ws[kk][c0+4];
      float av[4] = {a.x,a.y,a.z,a.w};
      float bv[8] = {b0.x,b0.y,b0.z,b0.w,b1.x,b1.y,b1.z,b1.w};
      #pragma unroll
      for (int i=0;i<4;i++)
        #pragma unroll
        for (int j=0;j<8;j++) acc[i][j] += av[i]*bv[j];
    }
  }
  #pragma unroll
  for (int i=0;i<4;i++){
    int r = row0 + r0 + i;
    float v[8];
    #pragma unroll
    for (int j=0;j<8;j++){
      float u = acc[i][j] + (bias ? bias[c0+j] : 0.f);
      v[j] = relu ? fmaxf(u, 0.f) : u;
    }
    if (r < M){
      if (Y){
        *(float4*)(Y + (size_t)r*128 + c0)     = make_float4(v[0],v[1],v[2],v[3]);
        *(float4*)(Y + (size_t)r*128 + c0 + 4) = make_float4(v[4],v[5],v[6],v[7]);
      }
      if (Ybf){
        uint4 pk;
        pk.x = (unsigned)f2bf(v[0]) | ((unsigned)f2bf(v[1])<<16);
        pk.y = (unsigned)f2bf(v[2]) | ((unsigned)f2bf(v[3])<<16);
        pk.z = (unsigned)f2bf(v[4]) | ((unsigned)f2bf(v[5])<<16);
        pk.w = (unsigned)f2bf(v[6]) | ((unsigned)f2bf(v[7])<<16);
        *(uint4*)(Ybf + (size_t)r*128 + c0) = pk;
      }
    }
    if (a_s){
      float s=0.f, d=0.f;
      #pragma unroll
      for (int j=0;j<8;j++){ s += v[j]*as_s[c0+j]; d += v[j]*ad_s[c0+j]; }
      #pragma unroll
      for (int off=1; off<16; off<<=1){ s += __shfl_xor(s,off); d += __shfl_xor(d,off); }
      if ((t & 15)==0 && r < M){ asrc[r]=s; adst[r]=d; }
    }
  }
}

// ---------------- GAT aggregation: wave per node ----------------
// R6: csr is uint4(src, ae0, ae1, -) — pass A is one fully-coalesced 16B
// load per edge (no random aedge gather). `layer` selects ae0/ae1.
__global__ __launch_bounds__(256) void k_agg(const int* __restrict__ rowptr, const uint4* __restrict__ csr,
    const float* __restrict__ asrc, const float* __restrict__ adst,
    const unsigned short* __restrict__ xlbf,
    const float* __restrict__ bias, float* __restrict__ out, int relu, int layer){
  int w = threadIdx.x >> 6;
  int lane = threadIdx.x & 63;
  int n = blockIdx.x * WPB + w;          // grid exact
  __shared__ float wbuf[WPB][MAXDEG];
  __shared__ int   sbuf[WPB][MAXDEG];
  const unsigned int* xb = (const unsigned int*)xlbf;  // row = 64 uints
  int s0 = rowptr[n], s1 = rowptr[n+1];
  int deg = s1 - s0;
  float adst_n = adst[n];
  // pass A: alphas (lane-parallel), running max + aedge sum (self-loop mean)
  float m_edge = -1e30f;
  float sae = 0.f;
  for (int base=0; base<deg; base+=64){
    int i = base + lane;
    float a = -1e30f;
    if (i < deg){
      uint4 p4 = csr[s0 + i];
      int sx = (int)p4.x;
      float ae = __uint_as_float(layer ? p4.z : p4.y);
      float av = lrelu(asrc[sx] + adst_n + ae);
      if (i < MAXDEG){ wbuf[w][i] = av; sbuf[w][i] = sx; }
      a = av;
      sae += ae;
    }
    for (int off=32; off; off>>=1) a = fmaxf(a, __shfl_xor(a, off));
    m_edge = fmaxf(m_edge, a);
  }
  for (int off=32; off; off>>=1) sae += __shfl_xor(sae, off);
  float aloop_n = sae / fmaxf((float)deg, 1.f);
  float al = lrelu(asrc[n] + adst_n + aloop_n);   // self-loop alpha
  float m = fmaxf(m_edge, al);
  // pass B: exp + sum
  float p = 0.f;
  for (int i=lane; i<deg; i+=64){
    float av;
    if (i < MAXDEG) av = wbuf[w][i];
    else { uint4 p4 = csr[s0+i];
           av = lrelu(asrc[p4.x] + adst_n + __uint_as_float(layer ? p4.z : p4.y)); }
    float ev = __expf(av - m);
    if (i < MAXDEG) wbuf[w][i] = ev;
    p += ev;
  }
  for (int off=32; off; off>>=1) p += __shfl_xor(p, off);
  float wl = __expf(al - m);
  float denom = p + wl;
  __syncthreads();   // cross-lane LDS visibility for pass C
  // pass C: 4-wide weighted gather of bf16 rows
  int g = lane >> 4, cl = lane & 15;   // group, column-slot (8 cols each)
  float acc[8];
  #pragma unroll
  for (int j=0;j<8;j++) acc[j]=0.f;
  if (g == 0){  // self-loop contribution (group 0 only)
    uint4 v = *(const uint4*)(xb + (size_t)n*64 + cl*4);
    unsigned int uu[4] = {v.x,v.y,v.z,v.w};
    #pragma unroll
    for (int q=0;q<4;q++){
      acc[2*q]   += wl * __uint_as_float(uu[q] << 16);
      acc[2*q+1] += wl * __uint_as_float(uu[q] & 0xFFFF0000u);
    }
  }
  for (int i=0; i<deg; i+=4){
    int idx = i + g;
    int sx = n; float we = 0.f;
    if (idx < deg){
      if (idx < MAXDEG){ sx = sbuf[w][idx]; we = wbuf[w][idx]; }
      else {
        uint4 p4 = csr[s0+idx]; sx = (int)p4.x;
        we = __expf(lrelu(asrc[sx] + adst_n + __uint_as_float(layer ? p4.z : p4.y)) - m);
      }
    }
    uint4 v = *(const uint4*)(xb + (size_t)sx*64 + cl*4);
    unsigned int uu[4] = {v.x,v.y,v.z,v.w};
    #pragma unroll
    for (int q=0;q<4;q++){
      acc[2*q]   += we * __uint_as_float(uu[q] << 16);
      acc[2*q+1] += we * __uint_as_float(uu[q] & 0xFFFF0000u);
    }
  }
  #pragma unroll
  for (int j=0;j<8;j++){
    acc[j] += __shfl_xor(acc[j], 16);
    acc[j] += __shfl_xor(acc[j], 32);
  }
  if (lane < 16){
    float inv = 1.f/denom;
    float4 b0 = *(const float4*)(bias + cl*8);
    float4 b1 = *(const float4*)(bias + cl*8 + 4);
    float o[8];
    o[0]=acc[0]*inv+b0.x; o[1]=acc[1]*inv+b0.y; o[2]=acc[2]*inv+b0.z; o[3]=acc[3]*inv+b0.w;
    o[4]=acc[4]*inv+b1.x; o[5]=acc[5]*inv+b1.y; o[6]=acc[6]*inv+b1.z; o[7]=acc[7]*inv+b1.w;
    if (relu){
      #pragma unroll
      for (int j=0;j<8;j++) o[j]=fmaxf(o[j],0.f);
    }
    *(float4*)(out + (size_t)n*128 + cl*8)     = make_float4(o[0],o[1],o[2],o[3]);
    *(float4*)(out + (size_t)n*128 + cl*8 + 4) = make_float4(o[4],o[5],o[6],o[7]);
  }
}

// ---------------- fused MLP: lin1 GEMM (+bias,relu) -> lin2 -> log_softmax ----------------
// R6: the 64-row GEMM tile matches k_lin2's 64-node block exactly. h stays
// in LDS (hs, stride 132); w2 restaged into Ws after the main loop. The A
// intermediate (51MB write + 51MB read) is eliminated.
__global__ __launch_bounds__(256) void k_mlp(const float* __restrict__ X, const float* __restrict__ W,
    const float* __restrict__ bias, const float* __restrict__ w2, const float* __restrict__ b2,
    float* __restrict__ out, int M){
  __shared__ float Xs[16][68];
  __shared__ float Ws[16][128];
  __shared__ float hs[64*132];
  __shared__ float b2s[16];
  int t = threadIdx.x;
  int row0 = blockIdx.x * 64;
  int tc = t & 15, tr = t >> 4;
  int c0 = tc*8, r0 = tr*4;
  int lr = t >> 2, lc = (t & 3) << 2;
  int wk = t >> 4, wc = (t & 15) * 8;
  float acc[4][8];
  #pragma unroll
  for (int i=0;i<4;i++)
    #pragma unroll
    for (int j=0;j<8;j++) acc[i][j]=0.f;
  int gr = row0 + lr;
  for (int k0=0; k0<128; k0+=16){
    float4 xv = make_float4(0.f,0.f,0.f,0.f);
    if (gr < M) xv = *(const float4*)(X + (size_t)gr*128 + k0 + lc);
    float4 wv0 = *(const float4*)(W + (size_t)(k0+wk)*128 + wc);
    float4 wv1 = *(const float4*)(W + (size_t)(k0+wk)*128 + wc + 4);
    __syncthreads();
    Xs[lc+0][lr]=xv.x; Xs[lc+1][lr]=xv.y; Xs[lc+2][lr]=xv.z; Xs[lc+3][lr]=xv.w;
    *(float4*)&Ws[wk][wc]   = wv0;
    *(float4*)&Ws[wk][wc+4] = wv1;
    __syncthreads();
    #pragma unroll
    for (int kk=0;kk<16;kk++){
      float4 a  = *(const float4*)&Xs[kk][r0];
      float4 b0 = *(const float4*)&Ws[kk][c0];
      float4 b1 = *(const float4*)&Ws[kk][c0+4];
      float av[4] = {a.x,a.y,a.z,a.w};
      float bv[8] = {b0.x,b0.y,b0.z,b0.w,b1.x,b1.y,b1.z,b1.w};
      #pragma unroll
      for (int i=0;i<4;i++)
        #pragma unroll
        for (int j=0;j<8;j++) acc[i][j] += av[i]*bv[j];
    }
  }
  __syncthreads();   // all Ws reads done before restage
  float* wflat = &Ws[0][0];
  #pragma unroll
  for (int i=0;i<2;i++) ((float4*)wflat)[t + i*256] = ((const float4*)w2)[t + i*256];
  if (t < 16) b2s[t] = b2[t];
  #pragma unroll
  for (int i=0;i<4;i++){
    float v[8];
    #pragma unroll
    for (int j=0;j<8;j++) v[j] = fmaxf(acc[i][j] + bias[c0+j], 0.f);
    int lrow = r0 + i;
    *(float4*)&hs[lrow*132 + c0]     = make_float4(v[0],v[1],v[2],v[3]);
    *(float4*)&hs[lrow*132 + c0 + 4] = make_float4(v[4],v[5],v[6],v[7]);
  }
  __syncthreads();
  int nl = t >> 2, cq = (t & 3) * 4;
  int n = row0 + nl;
  if (n < M){
    float a0=b2s[cq], a1=b2s[cq+1], a2=b2s[cq+2], a3=b2s[cq+3];
    const float* hp = &hs[nl*132];
    #pragma unroll 8
    for (int k=0;k<128;k++){
      float hv = hp[k];
      float4 w4 = *(const float4*)&wflat[k*16 + cq];
      a0 += hv*w4.x; a1 += hv*w4.y; a2 += hv*w4.z; a3 += hv*w4.w;
    }
    float m = fmaxf(fmaxf(a0,a1), fmaxf(a2,a3));
    m = fmaxf(m, __shfl_xor(m, 1));
    m = fmaxf(m, __shfl_xor(m, 2));
    float s = __expf(a0-m)+__expf(a1-m)+__expf(a2-m)+__expf(a3-m);
    s += __shfl_xor(s, 1);
    s += __shfl_xor(s, 2);
    float lse = m + __logf(s);
    *(float4*)(out + (size_t)n*16 + cq) = make_float4(a0-lse, a1-lse, a2-lse, a3-lse);
  }
}

extern "C" void kernel_launch(void* const* d_in, const int* in_sizes, int n_in,
                              void* d_out, int out_size, void* d_ws, size_t ws_size,
                              hipStream_t stream){
  const float* x    = (const float*)d_in[0];
  const float* eatt = (const float*)d_in[1];
  const float* W0   = (const float*)d_in[2];
  const float* as0  = (const float*)d_in[3];
  const float* ad0  = (const float*)d_in[4];
  const float* We0  = (const float*)d_in[5];
  const float* ae0  = (const float*)d_in[6];
  const float* b0   = (const float*)d_in[7];
  const float* W1   = (const float*)d_in[8];
  const float* as1  = (const float*)d_in[9];
  const float* ad1  = (const float*)d_in[10];
  const float* We1  = (const float*)d_in[11];
  const float* ae1  = (const float*)d_in[12];
  const float* b1   = (const float*)d_in[13];
  const float* l1w  = (const float*)d_in[14];
  const float* l1b  = (const float*)d_in[15];
  const float* l2w  = (const float*)d_in[16];
  const float* l2b  = (const float*)d_in[17];
  const int*   ei   = (const int*)d_in[18];
  const int* srcI = ei;
  const int* dstI = ei + N_EDGES;
  float* out = (float*)d_out;

  char* p = (char*)d_ws;
  auto alloc = [&](size_t bytes)->char*{ char* r = p; p += (bytes + 255) & ~255ull; return r; };
  unsigned short* Abf = (unsigned short*)alloc((size_t)N_NODES*128*2); // bf16 features
  float* B       = (float*)alloc((size_t)N_NODES*128*4);   // aggregation output
  float* asrc    = (float*)alloc((size_t)N_NODES*4);
  float* adst    = (float*)alloc((size_t)N_NODES*4);
  float* wea01   = (float*)alloc(128);
  int* deg     = (int*)alloc((size_t)N_NODES*4);
  int* fill    = (int*)alloc((size_t)N_NODES*4);
  int* rowptr  = (int*)alloc((size_t)(N_NODES+1)*4);
  uint4* csr   = (uint4*)alloc((size_t)N_EDGES*16);
  int* incl    = (int*)alloc((size_t)N_NODES*4);
  int* bsum    = (int*)alloc(512*4);
  int* bexcl   = (int*)alloc(512*4);

  const int NB_E = (N_EDGES+255)/256;   // 6250
  const int NB_N = (N_NODES+255)/256;   // 391
  const int NB_W = N_NODES/WPB;         // 25000 (exact)
  const int NB_G = (N_NODES+63)/64;     // 1563

  // ---- shared preprocessing ----
  hipMemsetAsync(deg,  0, (size_t)N_NODES*4, stream);
  hipMemsetAsync(fill, 0, (size_t)N_NODES*4, stream);
  k_deg   <<<NB_E,256,0,stream>>>(dstI, deg);
  k_scan_a<<<NB_N,256,0,stream>>>(deg, incl, bsum);
  k_scan_b<<<1,  512,0,stream>>>(bsum, bexcl, NB_N, We0, ae0, We1, ae1, wea01);
  k_scan_c<<<NB_N,256,0,stream>>>(incl, deg, bexcl, rowptr);
  k_fillf <<<NB_E,256,0,stream>>>(srcI, dstI, rowptr, fill, eatt, wea01, csr);

  // ---- layer 0 ----
  k_gemm <<<NB_G,256,0,stream>>>(x, W0, nullptr, nullptr, Abf, as0, ad0, asrc, adst, N_NODES, 0);
  k_agg  <<<NB_W,256,0,stream>>>(rowptr, csr, asrc, adst, Abf, b0, B, 1, 0);

  // ---- layer 1 ----
  k_gemm <<<NB_G,256,0,stream>>>(B, W1, nullptr, nullptr, Abf, as1, ad1, asrc, adst, N_NODES, 0);
  k_agg  <<<NB_W,256,0,stream>>>(rowptr, csr, asrc, adst, Abf, b1, B, 1, 1);

  // ---- post MLP (lin1 + lin2 + log_softmax fused) ----
  k_mlp  <<<NB_G,256,0,stream>>>(B, l1w, l1b, l2w, l2b, out, N_NODES);
}